// Round 10
// baseline (369.416 us; speedup 1.0000x reference)
//
#include <hip/hip_runtime.h>
#include <math.h>

#define DEVINL __device__ __forceinline__

// Deterministic block reduction of two double accumulators.
template<int NWAVES>
DEVINL void block_reduce_2d(double& a, double& b) {
  #pragma unroll
  for (int off = 32; off > 0; off >>= 1) {
    a += __shfl_down(a, off, 64);
    b += __shfl_down(b, off, 64);
  }
  __shared__ double sa[NWAVES], sb[NWAVES];
  const int tid = threadIdx.x;
  const int wid = tid >> 6;
  if ((tid & 63) == 0) { sa[wid] = a; sb[wid] = b; }
  __syncthreads();
  if (tid == 0) {
    double ta = 0.0, tb = 0.0;
    #pragma unroll
    for (int w = 0; w < NWAVES; ++w) { ta += sa[w]; tb += sb[w]; }
    a = ta; b = tb;
  }
}

// ---------------- Layer 1: x(16,1,196,3) * w1(128,1,6,1) s=(2,1) -> h1(16,128,96,3), fused BN+ReLU
__global__ __launch_bounds__(256) void k_conv1(
    const float* __restrict__ x, const float* __restrict__ w1,
    const float* __restrict__ g1, const float* __restrict__ b1,
    float* __restrict__ h1) {
  __shared__ float xlds[9408];          // whole x, 37.6KB
  const int co = blockIdx.x;    // 128
  const int tid = threadIdx.x;  // 256
  {
    float4* xd = (float4*)xlds;
    const float4* xs = (const float4*)x;
    #pragma unroll
    for (int k = 0; k < 10; ++k) {
      const int f = tid + k * 256;
      if (f < 2352) xd[f] = xs[f];
    }
  }
  float wv[6];
  #pragma unroll
  for (int i = 0; i < 6; ++i) wv[i] = w1[co * 6 + i];
  __syncthreads();

  float vals[18];               // 4608 positions / 256 threads
  double s = 0.0, sq = 0.0;
  #pragma unroll
  for (int k = 0; k < 18; ++k) {
    const int p = tid + k * 256;
    const int n = p / 288;
    const int r = p - n * 288;
    const int ho = r / 3;
    const int wo = r - ho * 3;
    const float* xb = xlds + n * 588 + (2 * ho) * 3 + wo;
    float acc = 0.f;
    #pragma unroll
    for (int i = 0; i < 6; ++i) acc += fabsf(xb[i * 3] - wv[i]);
    const float v = -acc;
    vals[k] = v;
    s += (double)v;
    sq += (double)v * (double)v;
  }
  block_reduce_2d<4>(s, sq);
  __shared__ float ssc, ssh;
  if (tid == 0) {
    const double mean = s * (1.0 / 4608.0);
    const double var  = sq * (1.0 / 4608.0) - mean * mean;
    const float rstd = (float)rsqrt(var + 1e-5);
    const float sc = g1[co] * rstd;
    ssc = sc;
    ssh = b1[co] - (float)mean * sc;
  }
  __syncthreads();
  const float sc = ssc, sh = ssh;
  #pragma unroll
  for (int k = 0; k < 18; ++k) {
    const int p = tid + k * 256;
    const int n = p / 288;
    const int r = p - n * 288;
    const int ho = r / 3;
    const int wo = r - ho * 3;
    h1[((n * 128 + co) * 96 + ho) * 3 + wo] = fmaxf(0.f, fmaf(vals[k], sc, sh));
  }
}

// ---------------- Layer 2 partial: h1(16,128,96,3) * w2(256,128,6,1) s=(2,1)
// Grid 512 = 64 co-groups(4) x 8 K-chunks(16 ci). 192 threads, active 184 = 8np x 23hp.
// Thread = n-pair: 4co x 2n x 6pos = 12 positions per w-fetch (halves broadcast tax).
// x: single-buffered LDS 2-ci chunks (8 stage phases). w: one-time LDS, 2x b128 broadcast.
__global__ __launch_bounds__(192) void k_conv2p(
    const float* __restrict__ h1, const float* __restrict__ w2,
    float* __restrict__ part2) {
  __shared__ float wlds[512];           // [ci 16][co 4][8 pad]
  __shared__ float4 xbuf[2336];         // [cil 2][16n][73 pad] float4
  const int bx = blockIdx.x;
  const int cg = bx >> 3, kc = bx & 7;
  const int co0 = cg * 4, ci0 = kc * 16;
  const int tid = threadIdx.x;          // 192
  #pragma unroll
  for (int f = tid; f < 512; f += 192) {
    const int cil = f >> 5, rem = f & 31, c = rem >> 3, kk = rem & 7;
    wlds[f] = (kk < 6) ? w2[(co0 + c) * 768 + (ci0 + cil) * 6 + kk] : 0.f;
  }
  const bool active = tid < 184;        // 8 np x 23 hp
  const int np = tid / 23, hp = tid - np * 23;
  const float4* h1v = (const float4*)h1;

  float acc[4][2][6];
  #pragma unroll
  for (int c = 0; c < 4; ++c)
    #pragma unroll
    for (int nn = 0; nn < 2; ++nn)
      #pragma unroll
      for (int o = 0; o < 6; ++o) acc[c][nn][o] = 0.f;

  const float4* wl4 = (const float4*)wlds;
  #pragma unroll 1
  for (int cc = 0; cc < 8; ++cc) {      // 8 chunks x 2 ci
    __syncthreads();                    // previous compute done before overwrite
    #pragma unroll
    for (int k = 0; k < 13; ++k) {
      const int f = tid + k * 192;
      if (f < 2336) {
        const int cil = f / 1168, rem = f - cil * 1168;
        const int nn = rem / 73, j = rem - nn * 73;
        if (j < 72)
          xbuf[f] = h1v[(size_t)nn * 9216 + (size_t)(ci0 + cc * 2 + cil) * 72 + j];
      }
    }
    __syncthreads();
    if (active) {
      #pragma unroll
      for (int cil = 0; cil < 2; ++cil) {
        const int cl = cc * 2 + cil;    // local ci 0..15
        float xf[2][24];
        #pragma unroll
        for (int nn = 0; nn < 2; ++nn) {
          const float4* xr = xbuf + cil * 1168 + (np * 2 + nn) * 73 + hp * 3;
          #pragma unroll
          for (int t = 0; t < 6; ++t) {
            const float4 q = xr[t];
            xf[nn][4 * t + 0] = q.x; xf[nn][4 * t + 1] = q.y;
            xf[nn][4 * t + 2] = q.z; xf[nn][4 * t + 3] = q.w;
          }
        }
        #pragma unroll
        for (int c = 0; c < 4; ++c) {
          const float4 wa = wl4[(cl * 4 + c) * 2];       // broadcast, 1 fetch / 72 taps
          const float4 wb = wl4[(cl * 4 + c) * 2 + 1];
          const float wv[6] = {wa.x, wa.y, wa.z, wa.w, wb.x, wb.y};
          #pragma unroll
          for (int nn = 0; nn < 2; ++nn)
            #pragma unroll
            for (int po = 0; po < 2; ++po)
              #pragma unroll
              for (int wo = 0; wo < 3; ++wo)
                #pragma unroll
                for (int i = 0; i < 6; ++i)
                  acc[c][nn][po * 3 + wo] += fabsf(xf[nn][(2 * po + i) * 3 + wo] - wv[i]);
        }
      }
    }
  }
  if (active) {
    #pragma unroll
    for (int c = 0; c < 4; ++c)
      #pragma unroll
      for (int nn = 0; nn < 2; ++nn)
        #pragma unroll
        for (int po = 0; po < 2; ++po)
          #pragma unroll
          for (int wo = 0; wo < 3; ++wo) {
            const int p = (np * 2 + nn) * 138 + (2 * hp + po) * 3 + wo;
            part2[(size_t)(kc * 256 + co0 + c) * 2208 + p] = acc[c][nn][po * 3 + wo];
          }
  }
}

// ---------------- Layer 2 combine: sum 8 K-partials, BN stats + apply -> h2(16,256,46,3)
__global__ __launch_bounds__(384) void k_combine2(
    const float* __restrict__ part2, const float* __restrict__ g2,
    const float* __restrict__ b2, float* __restrict__ h2) {
  const int co = blockIdx.x;    // 256
  const int tid = threadIdx.x;  // 384, active 368, 6 pos each
  const bool active = tid < 368;
  float v[6];
  double s = 0.0, sq = 0.0;
  #pragma unroll
  for (int k = 0; k < 6; ++k) {
    float sum = 0.f;
    if (active) {
      const int p = tid + k * 368;
      #pragma unroll
      for (int kc = 0; kc < 8; ++kc)
        sum += part2[(size_t)(kc * 256 + co) * 2208 + p];
    }
    const float val = -sum;
    v[k] = val;
    if (active) { s += (double)val; sq += (double)val * (double)val; }
  }
  block_reduce_2d<6>(s, sq);
  __shared__ float ssc, ssh;
  if (tid == 0) {
    const double mean = s * (1.0 / 2208.0);
    const double var  = sq * (1.0 / 2208.0) - mean * mean;
    const float rstd = (float)rsqrt(var + 1e-5);
    const float sc = g2[co] * rstd;
    ssc = sc;
    ssh = b2[co] - (float)mean * sc;
  }
  __syncthreads();
  if (active) {
    const float sc = ssc, sh = ssh;
    #pragma unroll
    for (int k = 0; k < 6; ++k) {
      const int p = tid + k * 368;
      const int n = p / 138, rem = p - n * 138;
      h2[n * 35328 + co * 138 + rem] = fmaxf(0.f, fmaf(v[k], sc, sh));
    }
  }
}

// ---------------- Layer 3 partial: h2(16,256,46,3) * w3(384,256,6,2) s=(2,1)
// Grid 768 = 48 co-groups(8) x 16 K-chunks(16 ci). 128 threads, active 112 = 16n x 7hot.
// Thread = (n, ho-triple): 8co x 3ho x 2wo = 6 positions per w-fetch; 21 = 7x3 exact (no tail).
// x: single-buffered LDS 4-ci chunks (4 stage phases), rows padded to 70 float2.
// w: one-time LDS [ci][co][12], 3x b128 broadcast per co per ci.
__global__ __launch_bounds__(128) void k_conv3p(
    const float* __restrict__ h2, const float* __restrict__ w3,
    float* __restrict__ part3) {
  __shared__ float wlds[1536];          // [ci 16][co 8][12]
  __shared__ float2 xbuf[4480];         // [cil 4][16n][70 pad] float2
  const int bx = blockIdx.x;
  const int cg = bx >> 4, kc = bx & 15;
  const int co0 = cg * 8, ci0 = kc * 16;
  const int tid = threadIdx.x;          // 128
  #pragma unroll
  for (int f = tid; f < 1536; f += 128) {
    const int cil = f / 96, rem = f - cil * 96, c = rem / 12, kk = rem - c * 12;
    wlds[f] = w3[(co0 + c) * 3072 + (ci0 + cil) * 12 + kk];
  }
  const bool active = tid < 112;        // 16 n x 7 hot
  const int n = tid / 7, hot = tid - n * 7;   // ho = 3hot + {0,1,2}
  const float2* h2v = (const float2*)h2;

  float acc[8][3][2];
  #pragma unroll
  for (int c = 0; c < 8; ++c)
    #pragma unroll
    for (int h = 0; h < 3; ++h) { acc[c][h][0] = 0.f; acc[c][h][1] = 0.f; }

  const float4* wl4 = (const float4*)wlds;
  #pragma unroll 1
  for (int cc = 0; cc < 4; ++cc) {      // 4 chunks x 4 ci
    __syncthreads();                    // previous compute done before overwrite
    #pragma unroll
    for (int k = 0; k < 35; ++k) {      // 35*128 = 4480 exact
      const int f = tid + k * 128;
      const int cil = f / 1120, rem = f - cil * 1120;
      const int nn = rem / 70, j = rem - nn * 70;
      if (j < 69)
        xbuf[f] = h2v[(size_t)nn * 17664 + (size_t)(ci0 + cc * 4 + cil) * 69 + j];
    }
    __syncthreads();
    if (active) {
      #pragma unroll
      for (int cil = 0; cil < 4; ++cil) {
        const int cl = cc * 4 + cil;    // local ci 0..15
        // 10-row window rows 6hot..6hot+9 = 30 floats, shared by the 3 ho.
        float xf[30];
        const float2* xr = xbuf + cil * 1120 + n * 70 + 9 * hot;
        #pragma unroll
        for (int t = 0; t < 15; ++t) {
          const float2 q = xr[t];
          xf[2 * t + 0] = q.x; xf[2 * t + 1] = q.y;
        }
        #pragma unroll
        for (int c = 0; c < 8; ++c) {
          const float4 w0 = wl4[(cl * 8 + c) * 3];       // broadcast, 1 fetch / 72 taps
          const float4 w1 = wl4[(cl * 8 + c) * 3 + 1];
          const float4 w2q = wl4[(cl * 8 + c) * 3 + 2];
          const float wv[12] = {w0.x, w0.y, w0.z, w0.w, w1.x, w1.y,
                                w1.z, w1.w, w2q.x, w2q.y, w2q.z, w2q.w};
          #pragma unroll
          for (int h = 0; h < 3; ++h)
            #pragma unroll
            for (int wo = 0; wo < 2; ++wo)
              #pragma unroll
              for (int i = 0; i < 6; ++i)
                #pragma unroll
                for (int j2 = 0; j2 < 2; ++j2)
                  acc[c][h][wo] += fabsf(xf[(2 * h + i) * 3 + wo + j2] - wv[i * 2 + j2]);
        }
      }
    }
  }
  if (active) {
    #pragma unroll
    for (int c = 0; c < 8; ++c)
      #pragma unroll
      for (int h = 0; h < 3; ++h) {
        const int ho = 3 * hot + h;     // 0..20, all valid
        #pragma unroll
        for (int wo = 0; wo < 2; ++wo) {
          const int p = n * 42 + ho * 2 + wo;
          part3[(size_t)(kc * 384 + co0 + c) * 672 + p] = acc[c][h][wo];
        }
      }
  }
}

// ---------------- Layer 3 combine: sum 16 K-partials, BN stats + apply -> h3(16,384,21,2)
__global__ __launch_bounds__(384) void k_combine3(
    const float* __restrict__ part3, const float* __restrict__ g3,
    const float* __restrict__ b3, float* __restrict__ h3) {
  const int co = blockIdx.x;    // 384
  const int tid = threadIdx.x;  // 384, active 336, 2 pos each
  const bool active = tid < 336;
  float v[2];
  double s = 0.0, sq = 0.0;
  #pragma unroll
  for (int k = 0; k < 2; ++k) {
    float sum = 0.f;
    if (active) {
      const int p = tid + k * 336;
      #pragma unroll
      for (int kc = 0; kc < 16; ++kc)
        sum += part3[(size_t)(kc * 384 + co) * 672 + p];
    }
    const float val = -sum;
    v[k] = val;
    if (active) { s += (double)val; sq += (double)val * (double)val; }
  }
  block_reduce_2d<6>(s, sq);
  __shared__ float ssc, ssh;
  if (tid == 0) {
    const double mean = s * (1.0 / 672.0);
    const double var  = sq * (1.0 / 672.0) - mean * mean;
    const float rstd = (float)rsqrt(var + 1e-5);
    const float sc = g3[co] * rstd;
    ssc = sc;
    ssh = b3[co] - (float)mean * sc;
  }
  __syncthreads();
  if (active) {
    const float sc = ssc, sh = ssh;
    #pragma unroll
    for (int k = 0; k < 2; ++k) {
      const int p = tid + k * 336;
      const int n = p / 42, rem = p - n * 42;
      h3[n * 16128 + co * 42 + rem] = fmaxf(0.f, fmaf(v[k], sc, sh));
    }
  }
}

// ---------------- FC partial: h3(16,16128) @ Wfc(6,16128)^T, K split 4 ways
__global__ __launch_bounds__(256) void k_fcp(
    const float* __restrict__ h3, const float* __restrict__ Wfc,
    float* __restrict__ hfcp) {
  const int bx = blockIdx.x;    // 384 = 96 pairs x 4
  const int pair = bx >> 2, q = bx & 3;
  const int n = pair / 6, o = pair - n * 6;
  const float4* xr = (const float4*)(h3 + n * 16128) + q * 1008;
  const float4* wr = (const float4*)(Wfc + o * 16128) + q * 1008;
  float sacc = 0.f;
  for (int k = threadIdx.x; k < 1008; k += 256) {
    const float4 xv = xr[k];
    const float4 wv = wr[k];
    sacc += xv.x * wv.x + xv.y * wv.y + xv.z * wv.z + xv.w * wv.w;
  }
  double d = (double)sacc, dummy = 0.0;
  block_reduce_2d<4>(d, dummy);
  if (threadIdx.x == 0) hfcp[bx] = (float)d;
}

// ---------------- Final: sum FC partials + bias, LayerNorm over 96, per-row L2 norm -> out(16,6)
__global__ __launch_bounds__(128) void k_final(
    const float* __restrict__ hfcp, const float* __restrict__ bfc,
    float* __restrict__ out) {
  __shared__ float ys[96];
  __shared__ float params[2];
  const int tid = threadIdx.x;
  float v = 0.f;
  if (tid < 96) {
    v = hfcp[tid * 4 + 0] + hfcp[tid * 4 + 1] + hfcp[tid * 4 + 2] + hfcp[tid * 4 + 3]
        + bfc[tid % 6];
    ys[tid] = v;
  }
  __syncthreads();
  if (tid == 0) {
    double s = 0.0, sq = 0.0;
    for (int i = 0; i < 96; ++i) { const double t = (double)ys[i]; s += t; sq += t * t; }
    const double mu = s / 96.0;
    const double var = sq / 96.0 - mu * mu;
    params[0] = (float)mu;
    params[1] = (float)rsqrt(var + 1e-5);
  }
  __syncthreads();
  const float y = (v - params[0]) * params[1];
  __syncthreads();
  if (tid < 96) ys[tid] = y;
  __syncthreads();
  if (tid < 96) {
    const int n = tid / 6;
    float ss = 0.f;
    #pragma unroll
    for (int k = 0; k < 6; ++k) { const float t = ys[n * 6 + k]; ss += t * t; }
    const float norm = sqrtf(ss);
    out[tid] = y / fmaxf(norm, 1e-12f);
  }
}

extern "C" void kernel_launch(void* const* d_in, const int* in_sizes, int n_in,
                              void* d_out, int out_size, void* d_ws, size_t ws_size,
                              hipStream_t stream) {
  const float* x   = (const float*)d_in[0];
  const float* w1  = (const float*)d_in[1];
  const float* g1  = (const float*)d_in[2];
  const float* b1  = (const float*)d_in[3];
  const float* w2  = (const float*)d_in[4];
  const float* g2  = (const float*)d_in[5];
  const float* b2  = (const float*)d_in[6];
  const float* w3  = (const float*)d_in[7];
  const float* g3  = (const float*)d_in[8];
  const float* b3  = (const float*)d_in[9];
  const float* Wfc = (const float*)d_in[10];
  const float* bfc = (const float*)d_in[11];

  float* ws   = (float*)d_ws;
  float* h1   = ws;                 // 589824
  float* h2   = h1 + 589824;        // 565248
  float* h3   = h2 + 565248;        // 258048
  float* hfcp = h3 + 258048;        // 384
  float* part = hfcp + 384;         // max(8*256*2208, 16*384*672) = 4521984
  float* out  = (float*)d_out;

  k_conv1   <<<128, 256, 0, stream>>>(x, w1, g1, b1, h1);
  k_conv2p  <<<512, 192, 0, stream>>>(h1, w2, part);
  k_combine2<<<256, 384, 0, stream>>>(part, g2, b2, h2);
  k_conv3p  <<<768, 128, 0, stream>>>(h2, w3, part);
  k_combine3<<<384, 384, 0, stream>>>(part, g3, b3, h3);
  k_fcp     <<<384, 256, 0, stream>>>(h3, Wfc, hfcp);
  k_final   <<<1, 128, 0, stream>>>(hfcp, bfc, out);
}

// Round 11
// 174.902 us; speedup vs baseline: 2.1121x; 2.1121x over previous
//
#include <hip/hip_runtime.h>
#include <math.h>

#define DEVINL __device__ __forceinline__

// Deterministic block reduction of two double accumulators.
template<int NWAVES>
DEVINL void block_reduce_2d(double& a, double& b) {
  #pragma unroll
  for (int off = 32; off > 0; off >>= 1) {
    a += __shfl_down(a, off, 64);
    b += __shfl_down(b, off, 64);
  }
  __shared__ double sa[NWAVES], sb[NWAVES];
  const int tid = threadIdx.x;
  const int wid = tid >> 6;
  if ((tid & 63) == 0) { sa[wid] = a; sb[wid] = b; }
  __syncthreads();
  if (tid == 0) {
    double ta = 0.0, tb = 0.0;
    #pragma unroll
    for (int w = 0; w < NWAVES; ++w) { ta += sa[w]; tb += sb[w]; }
    a = ta; b = tb;
  }
}

// ---------------- Layer 1: x(16,1,196,3) * w1(128,1,6,1) s=(2,1) -> h1(16,128,96,3), fused BN+ReLU
__global__ __launch_bounds__(256) void k_conv1(
    const float* __restrict__ x, const float* __restrict__ w1,
    const float* __restrict__ g1, const float* __restrict__ b1,
    float* __restrict__ h1) {
  __shared__ float xlds[9408];          // whole x, 37.6KB
  const int co = blockIdx.x;    // 128
  const int tid = threadIdx.x;  // 256
  {
    float4* xd = (float4*)xlds;
    const float4* xs = (const float4*)x;
    #pragma unroll
    for (int k = 0; k < 10; ++k) {
      const int f = tid + k * 256;
      if (f < 2352) xd[f] = xs[f];
    }
  }
  float wv[6];
  #pragma unroll
  for (int i = 0; i < 6; ++i) wv[i] = w1[co * 6 + i];
  __syncthreads();

  float vals[18];               // 4608 positions / 256 threads
  double s = 0.0, sq = 0.0;
  #pragma unroll
  for (int k = 0; k < 18; ++k) {
    const int p = tid + k * 256;
    const int n = p / 288;
    const int r = p - n * 288;
    const int ho = r / 3;
    const int wo = r - ho * 3;
    const float* xb = xlds + n * 588 + (2 * ho) * 3 + wo;
    float acc = 0.f;
    #pragma unroll
    for (int i = 0; i < 6; ++i) acc += fabsf(xb[i * 3] - wv[i]);
    const float v = -acc;
    vals[k] = v;
    s += (double)v;
    sq += (double)v * (double)v;
  }
  block_reduce_2d<4>(s, sq);
  __shared__ float ssc, ssh;
  if (tid == 0) {
    const double mean = s * (1.0 / 4608.0);
    const double var  = sq * (1.0 / 4608.0) - mean * mean;
    const float rstd = (float)rsqrt(var + 1e-5);
    const float sc = g1[co] * rstd;
    ssc = sc;
    ssh = b1[co] - (float)mean * sc;
  }
  __syncthreads();
  const float sc = ssc, sh = ssh;
  #pragma unroll
  for (int k = 0; k < 18; ++k) {
    const int p = tid + k * 256;
    const int n = p / 288;
    const int r = p - n * 288;
    const int ho = r / 3;
    const int wo = r - ho * 3;
    h1[((n * 128 + co) * 96 + ho) * 3 + wo] = fmaxf(0.f, fmaf(vals[k], sc, sh));
  }
}

// ---------------- Layer 2 partial: h1(16,128,96,3) * w2(256,128,6,1) s=(2,1)
// Grid 512 = 64 co-groups(4) x 8 K-chunks(16 ci). 384 threads, active 368 = 16n x 23hp.
// Thread = (n, hp): 4co x 2po x 3wo from a 24-float window. x: 1-ci double-buffered LDS
// (1 barrier/ci, reg prefetch r[3]). w: one-time LDS, 2x b128 wave-uniform broadcast.
__global__ __launch_bounds__(384) void k_conv2p(
    const float* __restrict__ h1, const float* __restrict__ w2,
    float* __restrict__ part2) {
  __shared__ float wlds[512];           // [ci 16][co 4][8 pad]
  __shared__ float4 xbuf[2][1168];      // [16n][73 pad]
  const int bx = blockIdx.x;
  const int cg = bx >> 3, kc = bx & 7;
  const int co0 = cg * 4, ci0 = kc * 16;
  const int tid = threadIdx.x;          // 384
  #pragma unroll
  for (int f = tid; f < 512; f += 384) {
    const int cil = f >> 5, rem = f & 31, c = rem >> 3, kk = rem & 7;
    wlds[f] = (kk < 6) ? w2[(co0 + c) * 768 + (ci0 + cil) * 6 + kk] : 0.f;
  }
  const bool active = tid < 368;        // 16n x 23hp
  const int n = tid / 23, hp = tid - n * 23;

  // stage slots: 3 float4 per thread per ci (3*384 = 1152 exact)
  int s_lds[3], s_g[3];
  #pragma unroll
  for (int k = 0; k < 3; ++k) {
    const int f = tid + k * 384;
    const int nn = f / 72, j = f - nn * 72;
    s_lds[k] = nn * 73 + j;
    s_g[k]   = nn * 9216 + j;           // + ci*72 at load
  }
  const float4* h1v = (const float4*)h1;

  float acc[4][6];
  #pragma unroll
  for (int c = 0; c < 4; ++c)
    #pragma unroll
    for (int o = 0; o < 6; ++o) acc[c][o] = 0.f;

  float4 r[3];
  #pragma unroll
  for (int k = 0; k < 3; ++k) r[k] = h1v[s_g[k] + ci0 * 72];
  #pragma unroll
  for (int k = 0; k < 3; ++k) xbuf[0][s_lds[k]] = r[k];
  #pragma unroll
  for (int k = 0; k < 3; ++k) r[k] = h1v[s_g[k] + (ci0 + 1) * 72];
  __syncthreads();

  const float4* wl4 = (const float4*)wlds;
  #pragma unroll 1
  for (int ci = 0; ci < 16; ++ci) {
    const float4* cur = xbuf[ci & 1];
    if (ci + 1 < 16) {
      float4* nxt = xbuf[(ci + 1) & 1];
      #pragma unroll
      for (int k = 0; k < 3; ++k) nxt[s_lds[k]] = r[k];
    }
    if (ci + 2 < 16) {
      #pragma unroll
      for (int k = 0; k < 3; ++k) r[k] = h1v[s_g[k] + (ci0 + ci + 2) * 72];
    }
    if (active) {
      const float4* xr = cur + n * 73 + hp * 3;
      float xf[24];
      #pragma unroll
      for (int t = 0; t < 6; ++t) {
        const float4 q = xr[t];
        xf[4 * t + 0] = q.x; xf[4 * t + 1] = q.y; xf[4 * t + 2] = q.z; xf[4 * t + 3] = q.w;
      }
      #pragma unroll
      for (int c = 0; c < 4; ++c) {
        const float4 wa = wl4[(ci * 4 + c) * 2];        // wave-uniform broadcast
        const float4 wb = wl4[(ci * 4 + c) * 2 + 1];
        const float wv[6] = {wa.x, wa.y, wa.z, wa.w, wb.x, wb.y};
        #pragma unroll
        for (int po = 0; po < 2; ++po)
          #pragma unroll
          for (int wo = 0; wo < 3; ++wo)
            #pragma unroll
            for (int i = 0; i < 6; ++i)
              acc[c][po * 3 + wo] += fabsf(xf[(2 * po + i) * 3 + wo] - wv[i]);
      }
    }
    __syncthreads();
  }
  if (active) {
    #pragma unroll
    for (int c = 0; c < 4; ++c)
      #pragma unroll
      for (int po = 0; po < 2; ++po)
        #pragma unroll
        for (int wo = 0; wo < 3; ++wo) {
          const int p = n * 138 + (2 * hp + po) * 3 + wo;
          part2[(size_t)(kc * 256 + co0 + c) * 2208 + p] = acc[c][po * 3 + wo];
        }
  }
}

// ---------------- Layer 2 combine: sum 8 K-partials, BN stats + apply -> h2(16,256,46,3)
__global__ __launch_bounds__(384) void k_combine2(
    const float* __restrict__ part2, const float* __restrict__ g2,
    const float* __restrict__ b2, float* __restrict__ h2) {
  const int co = blockIdx.x;    // 256
  const int tid = threadIdx.x;  // 384, active 368, 6 pos each
  const bool active = tid < 368;
  float v[6];
  double s = 0.0, sq = 0.0;
  #pragma unroll
  for (int k = 0; k < 6; ++k) {
    float sum = 0.f;
    if (active) {
      const int p = tid + k * 368;
      #pragma unroll
      for (int kc = 0; kc < 8; ++kc)
        sum += part2[(size_t)(kc * 256 + co) * 2208 + p];
    }
    const float val = -sum;
    v[k] = val;
    if (active) { s += (double)val; sq += (double)val * (double)val; }
  }
  block_reduce_2d<6>(s, sq);
  __shared__ float ssc, ssh;
  if (tid == 0) {
    const double mean = s * (1.0 / 2208.0);
    const double var  = sq * (1.0 / 2208.0) - mean * mean;
    const float rstd = (float)rsqrt(var + 1e-5);
    const float sc = g2[co] * rstd;
    ssc = sc;
    ssh = b2[co] - (float)mean * sc;
  }
  __syncthreads();
  if (active) {
    const float sc = ssc, sh = ssh;
    #pragma unroll
    for (int k = 0; k < 6; ++k) {
      const int p = tid + k * 368;
      const int n = p / 138, rem = p - n * 138;
      h2[n * 35328 + co * 138 + rem] = fmaxf(0.f, fmaf(v[k], sc, sh));
    }
  }
}

// ---------------- Layer 3 partial: h2(16,256,46,3) * w3(384,256,6,2) s=(2,1)
// Grid 1536 = 96 co-groups(4) x 16 K-chunks(16 ci) -> 6 blocks/CU, 12 waves/CU.
// 128 threads, active 112 = 16n x 7hot; thread = (n, ho-triple): 4co x 3ho x 2wo
// from a 30-float window (rows 6hot..6hot+9, shared by the 3 ho; 72 taps per w-fetch).
// x: 1-ci double-buffered LDS (1 barrier/ci, reg prefetch r[9]). w: one-time LDS, 3x b128 broadcast.
__global__ __launch_bounds__(128) void k_conv3p(
    const float* __restrict__ h2, const float* __restrict__ w3,
    float* __restrict__ part3) {
  __shared__ float wlds[768];           // [ci 16][co 4][12]
  __shared__ float2 xbuf[2][1120];      // [16n][70 pad]
  const int bx = blockIdx.x;
  const int cg = bx >> 4, kc = bx & 15;
  const int co0 = cg * 4, ci0 = kc * 16;
  const int tid = threadIdx.x;          // 128
  #pragma unroll
  for (int f = tid; f < 768; f += 128) {
    const int cil = f / 48, rem = f - cil * 48, c = rem / 12, kk = rem - c * 12;
    wlds[f] = w3[(co0 + c) * 3072 + (ci0 + cil) * 12 + kk];
  }
  const bool active = tid < 112;        // 16 n x 7 hot
  const int n = tid / 7, hot = tid - n * 7;   // ho = 3hot + {0,1,2}

  // stage slots: 9 float2 per thread per ci (8*128 + 80 = 1104; 9th slot for tid<80)
  int s_lds[9], s_g[9];
  const bool v9 = tid < 80;
  #pragma unroll
  for (int k = 0; k < 9; ++k) {
    const int f = tid + k * 128;
    const int nn = f / 69, j = f - nn * 69;
    s_lds[k] = nn * 70 + j;
    s_g[k]   = nn * 17664 + j;          // + ci*69 at load
  }
  const float2* h2v = (const float2*)h2;

  float acc[4][3][2];
  #pragma unroll
  for (int c = 0; c < 4; ++c)
    #pragma unroll
    for (int h = 0; h < 3; ++h) { acc[c][h][0] = 0.f; acc[c][h][1] = 0.f; }

  float2 r[9];
  #pragma unroll
  for (int k = 0; k < 8; ++k) r[k] = h2v[s_g[k] + ci0 * 69];
  if (v9) r[8] = h2v[s_g[8] + ci0 * 69];
  #pragma unroll
  for (int k = 0; k < 8; ++k) xbuf[0][s_lds[k]] = r[k];
  if (v9) xbuf[0][s_lds[8]] = r[8];
  #pragma unroll
  for (int k = 0; k < 8; ++k) r[k] = h2v[s_g[k] + (ci0 + 1) * 69];
  if (v9) r[8] = h2v[s_g[8] + (ci0 + 1) * 69];
  __syncthreads();

  const float4* wl4 = (const float4*)wlds;
  #pragma unroll 1
  for (int ci = 0; ci < 16; ++ci) {
    const float2* cur = xbuf[ci & 1];
    if (ci + 1 < 16) {
      float2* nxt = xbuf[(ci + 1) & 1];
      #pragma unroll
      for (int k = 0; k < 8; ++k) nxt[s_lds[k]] = r[k];
      if (v9) nxt[s_lds[8]] = r[8];
    }
    if (ci + 2 < 16) {
      #pragma unroll
      for (int k = 0; k < 8; ++k) r[k] = h2v[s_g[k] + (ci0 + ci + 2) * 69];
      if (v9) r[8] = h2v[s_g[8] + (ci0 + ci + 2) * 69];
    }
    if (active) {
      // 10-row window rows 6hot..6hot+9 = 30 floats (f2 9hot..9hot+14), shared by 3 ho
      float xf[30];
      const float2* xr = cur + n * 70 + 9 * hot;
      #pragma unroll
      for (int t = 0; t < 15; ++t) {
        const float2 q = xr[t];
        xf[2 * t + 0] = q.x; xf[2 * t + 1] = q.y;
      }
      #pragma unroll
      for (int c = 0; c < 4; ++c) {
        const float4 w0 = wl4[(ci * 4 + c) * 3];        // broadcast, 1 fetch / 72 taps
        const float4 w1 = wl4[(ci * 4 + c) * 3 + 1];
        const float4 w2q = wl4[(ci * 4 + c) * 3 + 2];
        const float wv[12] = {w0.x, w0.y, w0.z, w0.w, w1.x, w1.y,
                              w1.z, w1.w, w2q.x, w2q.y, w2q.z, w2q.w};
        #pragma unroll
        for (int h = 0; h < 3; ++h)
          #pragma unroll
          for (int wo = 0; wo < 2; ++wo)
            #pragma unroll
            for (int i = 0; i < 6; ++i)
              #pragma unroll
              for (int j2 = 0; j2 < 2; ++j2)
                acc[c][h][wo] += fabsf(xf[(2 * h + i) * 3 + wo + j2] - wv[i * 2 + j2]);
      }
    }
    __syncthreads();
  }
  if (active) {
    #pragma unroll
    for (int c = 0; c < 4; ++c)
      #pragma unroll
      for (int h = 0; h < 3; ++h) {
        const int ho = 3 * hot + h;     // 0..20, all valid
        #pragma unroll
        for (int wo = 0; wo < 2; ++wo) {
          const int p = n * 42 + ho * 2 + wo;
          part3[(size_t)(kc * 384 + co0 + c) * 672 + p] = acc[c][h][wo];
        }
      }
  }
}

// ---------------- Layer 3 combine: sum 16 K-partials, BN stats + apply -> h3(16,384,21,2)
__global__ __launch_bounds__(384) void k_combine3(
    const float* __restrict__ part3, const float* __restrict__ g3,
    const float* __restrict__ b3, float* __restrict__ h3) {
  const int co = blockIdx.x;    // 384
  const int tid = threadIdx.x;  // 384, active 336, 2 pos each
  const bool active = tid < 336;
  float v[2];
  double s = 0.0, sq = 0.0;
  #pragma unroll
  for (int k = 0; k < 2; ++k) {
    float sum = 0.f;
    if (active) {
      const int p = tid + k * 336;
      #pragma unroll
      for (int kc = 0; kc < 16; ++kc)
        sum += part3[(size_t)(kc * 384 + co) * 672 + p];
    }
    const float val = -sum;
    v[k] = val;
    if (active) { s += (double)val; sq += (double)val * (double)val; }
  }
  block_reduce_2d<6>(s, sq);
  __shared__ float ssc, ssh;
  if (tid == 0) {
    const double mean = s * (1.0 / 672.0);
    const double var  = sq * (1.0 / 672.0) - mean * mean;
    const float rstd = (float)rsqrt(var + 1e-5);
    const float sc = g3[co] * rstd;
    ssc = sc;
    ssh = b3[co] - (float)mean * sc;
  }
  __syncthreads();
  if (active) {
    const float sc = ssc, sh = ssh;
    #pragma unroll
    for (int k = 0; k < 2; ++k) {
      const int p = tid + k * 336;
      const int n = p / 42, rem = p - n * 42;
      h3[n * 16128 + co * 42 + rem] = fmaxf(0.f, fmaf(v[k], sc, sh));
    }
  }
}

// ---------------- FC partial: h3(16,16128) @ Wfc(6,16128)^T, K split 4 ways
__global__ __launch_bounds__(256) void k_fcp(
    const float* __restrict__ h3, const float* __restrict__ Wfc,
    float* __restrict__ hfcp) {
  const int bx = blockIdx.x;    // 384 = 96 pairs x 4
  const int pair = bx >> 2, q = bx & 3;
  const int n = pair / 6, o = pair - n * 6;
  const float4* xr = (const float4*)(h3 + n * 16128) + q * 1008;
  const float4* wr = (const float4*)(Wfc + o * 16128) + q * 1008;
  float sacc = 0.f;
  for (int k = threadIdx.x; k < 1008; k += 256) {
    const float4 xv = xr[k];
    const float4 wv = wr[k];
    sacc += xv.x * wv.x + xv.y * wv.y + xv.z * wv.z + xv.w * wv.w;
  }
  double d = (double)sacc, dummy = 0.0;
  block_reduce_2d<4>(d, dummy);
  if (threadIdx.x == 0) hfcp[bx] = (float)d;
}

// ---------------- Final: sum FC partials + bias, LayerNorm over 96, per-row L2 norm -> out(16,6)
__global__ __launch_bounds__(128) void k_final(
    const float* __restrict__ hfcp, const float* __restrict__ bfc,
    float* __restrict__ out) {
  __shared__ float ys[96];
  __shared__ float params[2];
  const int tid = threadIdx.x;
  float v = 0.f;
  if (tid < 96) {
    v = hfcp[tid * 4 + 0] + hfcp[tid * 4 + 1] + hfcp[tid * 4 + 2] + hfcp[tid * 4 + 3]
        + bfc[tid % 6];
    ys[tid] = v;
  }
  __syncthreads();
  if (tid == 0) {
    double s = 0.0, sq = 0.0;
    for (int i = 0; i < 96; ++i) { const double t = (double)ys[i]; s += t; sq += t * t; }
    const double mu = s / 96.0;
    const double var = sq / 96.0 - mu * mu;
    params[0] = (float)mu;
    params[1] = (float)rsqrt(var + 1e-5);
  }
  __syncthreads();
  const float y = (v - params[0]) * params[1];
  __syncthreads();
  if (tid < 96) ys[tid] = y;
  __syncthreads();
  if (tid < 96) {
    const int n = tid / 6;
    float ss = 0.f;
    #pragma unroll
    for (int k = 0; k < 6; ++k) { const float t = ys[n * 6 + k]; ss += t * t; }
    const float norm = sqrtf(ss);
    out[tid] = y / fmaxf(norm, 1e-12f);
  }
}

extern "C" void kernel_launch(void* const* d_in, const int* in_sizes, int n_in,
                              void* d_out, int out_size, void* d_ws, size_t ws_size,
                              hipStream_t stream) {
  const float* x   = (const float*)d_in[0];
  const float* w1  = (const float*)d_in[1];
  const float* g1  = (const float*)d_in[2];
  const float* b1  = (const float*)d_in[3];
  const float* w2  = (const float*)d_in[4];
  const float* g2  = (const float*)d_in[5];
  const float* b2  = (const float*)d_in[6];
  const float* w3  = (const float*)d_in[7];
  const float* g3  = (const float*)d_in[8];
  const float* b3  = (const float*)d_in[9];
  const float* Wfc = (const float*)d_in[10];
  const float* bfc = (const float*)d_in[11];

  float* ws   = (float*)d_ws;
  float* h1   = ws;                 // 589824
  float* h2   = h1 + 589824;        // 565248
  float* h3   = h2 + 565248;        // 258048
  float* hfcp = h3 + 258048;        // 384
  float* part = hfcp + 384;         // max(8*256*2208, 16*384*672) = 4521984
  float* out  = (float*)d_out;

  k_conv1   <<<128, 256, 0, stream>>>(x, w1, g1, b1, h1);
  k_conv2p  <<<512, 384, 0, stream>>>(h1, w2, part);
  k_combine2<<<256, 384, 0, stream>>>(part, g2, b2, h2);
  k_conv3p  <<<1536, 128, 0, stream>>>(h2, w3, part);
  k_combine3<<<384, 384, 0, stream>>>(part, g3, b3, h3);
  k_fcp     <<<384, 256, 0, stream>>>(h3, Wfc, hfcp);
  k_final   <<<1, 128, 0, stream>>>(hfcp, bfc, out);
}

// Round 12
// 153.071 us; speedup vs baseline: 2.4134x; 1.1426x over previous
//
#include <hip/hip_runtime.h>
#include <math.h>

#define DEVINL __device__ __forceinline__

// Deterministic block reduction of two double accumulators.
template<int NWAVES>
DEVINL void block_reduce_2d(double& a, double& b) {
  #pragma unroll
  for (int off = 32; off > 0; off >>= 1) {
    a += __shfl_down(a, off, 64);
    b += __shfl_down(b, off, 64);
  }
  __shared__ double sa[NWAVES], sb[NWAVES];
  const int tid = threadIdx.x;
  const int wid = tid >> 6;
  if ((tid & 63) == 0) { sa[wid] = a; sb[wid] = b; }
  __syncthreads();
  if (tid == 0) {
    double ta = 0.0, tb = 0.0;
    #pragma unroll
    for (int w = 0; w < NWAVES; ++w) { ta += sa[w]; tb += sb[w]; }
    a = ta; b = tb;
  }
}

// ---------------- Layer 1: x(16,1,196,3) * w1(128,1,6,1) s=(2,1) -> h1(16,128,96,3), fused BN+ReLU
__global__ __launch_bounds__(256) void k_conv1(
    const float* __restrict__ x, const float* __restrict__ w1,
    const float* __restrict__ g1, const float* __restrict__ b1,
    float* __restrict__ h1) {
  __shared__ float xlds[9408];          // whole x, 37.6KB
  const int co = blockIdx.x;    // 128
  const int tid = threadIdx.x;  // 256
  {
    float4* xd = (float4*)xlds;
    const float4* xs = (const float4*)x;
    #pragma unroll
    for (int k = 0; k < 10; ++k) {
      const int f = tid + k * 256;
      if (f < 2352) xd[f] = xs[f];
    }
  }
  float wv[6];
  #pragma unroll
  for (int i = 0; i < 6; ++i) wv[i] = w1[co * 6 + i];
  __syncthreads();

  float vals[18];               // 4608 positions / 256 threads
  double s = 0.0, sq = 0.0;
  #pragma unroll
  for (int k = 0; k < 18; ++k) {
    const int p = tid + k * 256;
    const int n = p / 288;
    const int r = p - n * 288;
    const int ho = r / 3;
    const int wo = r - ho * 3;
    const float* xb = xlds + n * 588 + (2 * ho) * 3 + wo;
    float d0 = fabsf(xb[0]  - wv[0]);
    float d1 = fabsf(xb[3]  - wv[1]);
    float d2 = fabsf(xb[6]  - wv[2]);
    float d3 = fabsf(xb[9]  - wv[3]);
    float d4 = fabsf(xb[12] - wv[4]);
    float d5 = fabsf(xb[15] - wv[5]);
    const float v = -(((d0 + d1) + (d2 + d3)) + (d4 + d5));
    vals[k] = v;
    s += (double)v;
    sq += (double)v * (double)v;
  }
  block_reduce_2d<4>(s, sq);
  __shared__ float ssc, ssh;
  if (tid == 0) {
    const double mean = s * (1.0 / 4608.0);
    const double var  = sq * (1.0 / 4608.0) - mean * mean;
    const float rstd = (float)rsqrt(var + 1e-5);
    const float sc = g1[co] * rstd;
    ssc = sc;
    ssh = b1[co] - (float)mean * sc;
  }
  __syncthreads();
  const float sc = ssc, sh = ssh;
  #pragma unroll
  for (int k = 0; k < 18; ++k) {
    const int p = tid + k * 256;
    const int n = p / 288;
    const int r = p - n * 288;
    const int ho = r / 3;
    const int wo = r - ho * 3;
    h1[((n * 128 + co) * 96 + ho) * 3 + wo] = fmaxf(0.f, fmaf(vals[k], sc, sh));
  }
}

// ---------------- Layer 2 partial: h1(16,128,96,3) * w2(256,128,6,1) s=(2,1)
// Grid 512 = 64 co-groups(4) x 8 K-chunks(16 ci). 384 threads, active 368 = 16n x 23hp.
// Tree-sum accumulation (ILP). x: 1-ci dbuf LDS. w: one-time LDS, b128 broadcast.
__global__ __launch_bounds__(384) void k_conv2p(
    const float* __restrict__ h1, const float* __restrict__ w2,
    float* __restrict__ part2) {
  __shared__ float wlds[512];           // [ci 16][co 4][8 pad]
  __shared__ float4 xbuf[2][1168];      // [16n][73 pad]
  const int bx = blockIdx.x;
  const int cg = bx >> 3, kc = bx & 7;
  const int co0 = cg * 4, ci0 = kc * 16;
  const int tid = threadIdx.x;          // 384
  #pragma unroll
  for (int f = tid; f < 512; f += 384) {
    const int cil = f >> 5, rem = f & 31, c = rem >> 3, kk = rem & 7;
    wlds[f] = (kk < 6) ? w2[(co0 + c) * 768 + (ci0 + cil) * 6 + kk] : 0.f;
  }
  const bool active = tid < 368;        // 16n x 23hp
  const int n = tid / 23, hp = tid - n * 23;

  int s_lds[3], s_g[3];
  #pragma unroll
  for (int k = 0; k < 3; ++k) {
    const int f = tid + k * 384;
    const int nn = f / 72, j = f - nn * 72;
    s_lds[k] = nn * 73 + j;
    s_g[k]   = nn * 9216 + j;           // + ci*72 at load
  }
  const float4* h1v = (const float4*)h1;

  float acc[4][6];
  #pragma unroll
  for (int c = 0; c < 4; ++c)
    #pragma unroll
    for (int o = 0; o < 6; ++o) acc[c][o] = 0.f;

  float4 r[3];
  #pragma unroll
  for (int k = 0; k < 3; ++k) r[k] = h1v[s_g[k] + ci0 * 72];
  #pragma unroll
  for (int k = 0; k < 3; ++k) xbuf[0][s_lds[k]] = r[k];
  #pragma unroll
  for (int k = 0; k < 3; ++k) r[k] = h1v[s_g[k] + (ci0 + 1) * 72];
  __syncthreads();

  const float4* wl4 = (const float4*)wlds;
  #pragma unroll 1
  for (int ci = 0; ci < 16; ++ci) {
    const float4* cur = xbuf[ci & 1];
    if (ci + 1 < 16) {
      float4* nxt = xbuf[(ci + 1) & 1];
      #pragma unroll
      for (int k = 0; k < 3; ++k) nxt[s_lds[k]] = r[k];
    }
    if (ci + 2 < 16) {
      #pragma unroll
      for (int k = 0; k < 3; ++k) r[k] = h1v[s_g[k] + (ci0 + ci + 2) * 72];
    }
    if (active) {
      const float4* xr = cur + n * 73 + hp * 3;
      float xf[24];
      #pragma unroll
      for (int t = 0; t < 6; ++t) {
        const float4 q = xr[t];
        xf[4 * t + 0] = q.x; xf[4 * t + 1] = q.y; xf[4 * t + 2] = q.z; xf[4 * t + 3] = q.w;
      }
      #pragma unroll
      for (int c = 0; c < 4; ++c) {
        const float4 wa = wl4[(ci * 4 + c) * 2];        // wave-uniform broadcast
        const float4 wb = wl4[(ci * 4 + c) * 2 + 1];
        const float wv[6] = {wa.x, wa.y, wa.z, wa.w, wb.x, wb.y};
        #pragma unroll
        for (int po = 0; po < 2; ++po)
          #pragma unroll
          for (int wo = 0; wo < 3; ++wo) {
            float d0 = fabsf(xf[(2 * po + 0) * 3 + wo] - wv[0]);
            float d1 = fabsf(xf[(2 * po + 1) * 3 + wo] - wv[1]);
            float d2 = fabsf(xf[(2 * po + 2) * 3 + wo] - wv[2]);
            float d3 = fabsf(xf[(2 * po + 3) * 3 + wo] - wv[3]);
            float d4 = fabsf(xf[(2 * po + 4) * 3 + wo] - wv[4]);
            float d5 = fabsf(xf[(2 * po + 5) * 3 + wo] - wv[5]);
            acc[c][po * 3 + wo] += ((d0 + d1) + (d2 + d3)) + (d4 + d5);
          }
      }
    }
    __syncthreads();
  }
  if (active) {
    #pragma unroll
    for (int c = 0; c < 4; ++c)
      #pragma unroll
      for (int po = 0; po < 2; ++po)
        #pragma unroll
        for (int wo = 0; wo < 3; ++wo) {
          const int p = n * 138 + (2 * hp + po) * 3 + wo;
          part2[(size_t)(kc * 256 + co0 + c) * 2208 + p] = acc[c][po * 3 + wo];
        }
  }
}

// ---------------- Layer 2 combine: sum 8 K-partials, BN stats + apply -> h2(16,256,46,3)
__global__ __launch_bounds__(384) void k_combine2(
    const float* __restrict__ part2, const float* __restrict__ g2,
    const float* __restrict__ b2, float* __restrict__ h2) {
  const int co = blockIdx.x;    // 256
  const int tid = threadIdx.x;  // 384, active 368, 6 pos each
  const bool active = tid < 368;
  float v[6];
  double s = 0.0, sq = 0.0;
  #pragma unroll
  for (int k = 0; k < 6; ++k) {
    float sum = 0.f;
    if (active) {
      const int p = tid + k * 368;
      #pragma unroll
      for (int kc = 0; kc < 8; ++kc)
        sum += part2[(size_t)(kc * 256 + co) * 2208 + p];
    }
    const float val = -sum;
    v[k] = val;
    if (active) { s += (double)val; sq += (double)val * (double)val; }
  }
  block_reduce_2d<6>(s, sq);
  __shared__ float ssc, ssh;
  if (tid == 0) {
    const double mean = s * (1.0 / 2208.0);
    const double var  = sq * (1.0 / 2208.0) - mean * mean;
    const float rstd = (float)rsqrt(var + 1e-5);
    const float sc = g2[co] * rstd;
    ssc = sc;
    ssh = b2[co] - (float)mean * sc;
  }
  __syncthreads();
  if (active) {
    const float sc = ssc, sh = ssh;
    #pragma unroll
    for (int k = 0; k < 6; ++k) {
      const int p = tid + k * 368;
      const int n = p / 138, rem = p - n * 138;
      h2[n * 35328 + co * 138 + rem] = fmaxf(0.f, fmaf(v[k], sc, sh));
    }
  }
}

// ---------------- Layer 3 partial: h2(16,256,46,3) * w3(384,256,6,2) s=(2,1)
// Grid 3072 = 2 n-halves x 96 co-groups(4) x 16 K-chunks(16 ci). 128 threads, active 112
// = 8n x 7hot x 2co-halves; thread = 2co x 3ho x 2wo from a 30-float window.
// Tree-sum accumulation (ILP). x: 1-ci dbuf LDS [8n][71 pad]. w: one-time LDS, 3x b128 broadcast.
__global__ __launch_bounds__(128) void k_conv3p(
    const float* __restrict__ h2, const float* __restrict__ w3,
    float* __restrict__ part3) {
  __shared__ float wlds[768];           // [ci 16][co 4][12]
  __shared__ float2 xbuf[2][568];       // [8n][71 pad]
  const int bx = blockIdx.x;
  const int kc = bx & 15;
  const int rbx = bx >> 4;
  const int cg = rbx % 96;
  const int nh = rbx / 96;              // 0 or 1
  const int co0 = cg * 4, ci0 = kc * 16, n0 = nh * 8;
  const int tid = threadIdx.x;          // 128
  #pragma unroll
  for (int f = tid; f < 768; f += 128) {
    const int cil = f / 48, rem = f - cil * 48, c = rem / 12, kk = rem - c * 12;
    wlds[f] = w3[(co0 + c) * 3072 + (ci0 + cil) * 12 + kk];
  }
  const bool active = tid < 112;        // 8n x 7hot x 2ch
  const int n = tid / 14;               // 0..7
  const int rem14 = tid - n * 14;
  const int hot = rem14 >> 1;           // 0..6
  const int ch = rem14 & 1;             // co-half

  // stage slots: 5 float2 per thread per ci (4*128 + 40 = 552 = 8n*69)
  int s_lds[5], s_g[5];
  const bool v5 = tid < 40;
  #pragma unroll
  for (int k = 0; k < 5; ++k) {
    const int f = tid + k * 128;
    const int nn = f / 69, j = f - nn * 69;
    s_lds[k] = nn * 71 + j;
    s_g[k]   = (n0 + nn) * 17664 + j;   // + ci*69 at load
  }
  const float2* h2v = (const float2*)h2;

  float acc[2][3][2];
  #pragma unroll
  for (int c = 0; c < 2; ++c)
    #pragma unroll
    for (int h = 0; h < 3; ++h) { acc[c][h][0] = 0.f; acc[c][h][1] = 0.f; }

  float2 r[5];
  #pragma unroll
  for (int k = 0; k < 4; ++k) r[k] = h2v[s_g[k] + ci0 * 69];
  if (v5) r[4] = h2v[s_g[4] + ci0 * 69];
  #pragma unroll
  for (int k = 0; k < 4; ++k) xbuf[0][s_lds[k]] = r[k];
  if (v5) xbuf[0][s_lds[4]] = r[4];
  #pragma unroll
  for (int k = 0; k < 4; ++k) r[k] = h2v[s_g[k] + (ci0 + 1) * 69];
  if (v5) r[4] = h2v[s_g[4] + (ci0 + 1) * 69];
  __syncthreads();

  const float4* wl4 = (const float4*)wlds;
  #pragma unroll 1
  for (int ci = 0; ci < 16; ++ci) {
    const float2* cur = xbuf[ci & 1];
    if (ci + 1 < 16) {
      float2* nxt = xbuf[(ci + 1) & 1];
      #pragma unroll
      for (int k = 0; k < 4; ++k) nxt[s_lds[k]] = r[k];
      if (v5) nxt[s_lds[4]] = r[4];
    }
    if (ci + 2 < 16) {
      #pragma unroll
      for (int k = 0; k < 4; ++k) r[k] = h2v[s_g[k] + (ci0 + ci + 2) * 69];
      if (v5) r[4] = h2v[s_g[4] + (ci0 + ci + 2) * 69];
    }
    if (active) {
      // 10-row window rows 6hot..6hot+9 = 30 floats, shared by 3 ho (both co of this thread)
      float xf[30];
      const float2* xr = cur + n * 71 + 9 * hot;
      #pragma unroll
      for (int t = 0; t < 15; ++t) {
        const float2 q = xr[t];
        xf[2 * t + 0] = q.x; xf[2 * t + 1] = q.y;
      }
      #pragma unroll
      for (int c = 0; c < 2; ++c) {
        const int cg4 = ch * 2 + c;     // co index within group 0..3
        const float4 w0 = wl4[(ci * 4 + cg4) * 3];      // broadcast
        const float4 w1 = wl4[(ci * 4 + cg4) * 3 + 1];
        const float4 w2q = wl4[(ci * 4 + cg4) * 3 + 2];
        const float wv[12] = {w0.x, w0.y, w0.z, w0.w, w1.x, w1.y,
                              w1.z, w1.w, w2q.x, w2q.y, w2q.z, w2q.w};
        #pragma unroll
        for (int h = 0; h < 3; ++h)
          #pragma unroll
          for (int wo = 0; wo < 2; ++wo) {
            float d[12];
            #pragma unroll
            for (int i = 0; i < 6; ++i) {
              d[2 * i]     = fabsf(xf[(2 * h + i) * 3 + wo]     - wv[2 * i]);
              d[2 * i + 1] = fabsf(xf[(2 * h + i) * 3 + wo + 1] - wv[2 * i + 1]);
            }
            const float s0 = (d[0] + d[1]) + (d[2] + d[3]);
            const float s1 = (d[4] + d[5]) + (d[6] + d[7]);
            const float s2 = (d[8] + d[9]) + (d[10] + d[11]);
            acc[c][h][wo] += (s0 + s1) + s2;
          }
      }
    }
    __syncthreads();
  }
  if (active) {
    #pragma unroll
    for (int c = 0; c < 2; ++c)
      #pragma unroll
      for (int h = 0; h < 3; ++h) {
        const int ho = 3 * hot + h;     // 0..20
        #pragma unroll
        for (int wo = 0; wo < 2; ++wo) {
          const int p = (n0 + n) * 42 + ho * 2 + wo;
          part3[(size_t)(kc * 384 + co0 + ch * 2 + c) * 672 + p] = acc[c][h][wo];
        }
      }
  }
}

// ---------------- Layer 3 combine: sum 16 K-partials, BN stats + apply -> h3(16,384,21,2)
__global__ __launch_bounds__(384) void k_combine3(
    const float* __restrict__ part3, const float* __restrict__ g3,
    const float* __restrict__ b3, float* __restrict__ h3) {
  const int co = blockIdx.x;    // 384
  const int tid = threadIdx.x;  // 384, active 336, 2 pos each
  const bool active = tid < 336;
  float v[2];
  double s = 0.0, sq = 0.0;
  #pragma unroll
  for (int k = 0; k < 2; ++k) {
    float sum = 0.f;
    if (active) {
      const int p = tid + k * 336;
      #pragma unroll
      for (int kc = 0; kc < 16; ++kc)
        sum += part3[(size_t)(kc * 384 + co) * 672 + p];
    }
    const float val = -sum;
    v[k] = val;
    if (active) { s += (double)val; sq += (double)val * (double)val; }
  }
  block_reduce_2d<6>(s, sq);
  __shared__ float ssc, ssh;
  if (tid == 0) {
    const double mean = s * (1.0 / 672.0);
    const double var  = sq * (1.0 / 672.0) - mean * mean;
    const float rstd = (float)rsqrt(var + 1e-5);
    const float sc = g3[co] * rstd;
    ssc = sc;
    ssh = b3[co] - (float)mean * sc;
  }
  __syncthreads();
  if (active) {
    const float sc = ssc, sh = ssh;
    #pragma unroll
    for (int k = 0; k < 2; ++k) {
      const int p = tid + k * 336;
      const int n = p / 42, rem = p - n * 42;
      h3[n * 16128 + co * 42 + rem] = fmaxf(0.f, fmaf(v[k], sc, sh));
    }
  }
}

// ---------------- FC partial: h3(16,16128) @ Wfc(6,16128)^T, K split 4 ways
__global__ __launch_bounds__(256) void k_fcp(
    const float* __restrict__ h3, const float* __restrict__ Wfc,
    float* __restrict__ hfcp) {
  const int bx = blockIdx.x;    // 384 = 96 pairs x 4
  const int pair = bx >> 2, q = bx & 3;
  const int n = pair / 6, o = pair - n * 6;
  const float4* xr = (const float4*)(h3 + n * 16128) + q * 1008;
  const float4* wr = (const float4*)(Wfc + o * 16128) + q * 1008;
  float sacc = 0.f;
  for (int k = threadIdx.x; k < 1008; k += 256) {
    const float4 xv = xr[k];
    const float4 wv = wr[k];
    sacc += xv.x * wv.x + xv.y * wv.y + xv.z * wv.z + xv.w * wv.w;
  }
  double d = (double)sacc, dummy = 0.0;
  block_reduce_2d<4>(d, dummy);
  if (threadIdx.x == 0) hfcp[bx] = (float)d;
}

// ---------------- Final: sum FC partials + bias, LayerNorm over 96, per-row L2 norm -> out(16,6)
__global__ __launch_bounds__(128) void k_final(
    const float* __restrict__ hfcp, const float* __restrict__ bfc,
    float* __restrict__ out) {
  __shared__ float ys[96];
  __shared__ float params[2];
  const int tid = threadIdx.x;
  float v = 0.f;
  if (tid < 96) {
    v = hfcp[tid * 4 + 0] + hfcp[tid * 4 + 1] + hfcp[tid * 4 + 2] + hfcp[tid * 4 + 3]
        + bfc[tid % 6];
    ys[tid] = v;
  }
  __syncthreads();
  if (tid == 0) {
    double s = 0.0, sq = 0.0;
    for (int i = 0; i < 96; ++i) { const double t = (double)ys[i]; s += t; sq += t * t; }
    const double mu = s / 96.0;
    const double var = sq / 96.0 - mu * mu;
    params[0] = (float)mu;
    params[1] = (float)rsqrt(var + 1e-5);
  }
  __syncthreads();
  const float y = (v - params[0]) * params[1];
  __syncthreads();
  if (tid < 96) ys[tid] = y;
  __syncthreads();
  if (tid < 96) {
    const int n = tid / 6;
    float ss = 0.f;
    #pragma unroll
    for (int k = 0; k < 6; ++k) { const float t = ys[n * 6 + k]; ss += t * t; }
    const float norm = sqrtf(ss);
    out[tid] = y / fmaxf(norm, 1e-12f);
  }
}

extern "C" void kernel_launch(void* const* d_in, const int* in_sizes, int n_in,
                              void* d_out, int out_size, void* d_ws, size_t ws_size,
                              hipStream_t stream) {
  const float* x   = (const float*)d_in[0];
  const float* w1  = (const float*)d_in[1];
  const float* g1  = (const float*)d_in[2];
  const float* b1  = (const float*)d_in[3];
  const float* w2  = (const float*)d_in[4];
  const float* g2  = (const float*)d_in[5];
  const float* b2  = (const float*)d_in[6];
  const float* w3  = (const float*)d_in[7];
  const float* g3  = (const float*)d_in[8];
  const float* b3  = (const float*)d_in[9];
  const float* Wfc = (const float*)d_in[10];
  const float* bfc = (const float*)d_in[11];

  float* ws   = (float*)d_ws;
  float* h1   = ws;                 // 589824
  float* h2   = h1 + 589824;        // 565248
  float* h3   = h2 + 565248;        // 258048
  float* hfcp = h3 + 258048;        // 384
  float* part = hfcp + 384;         // max(8*256*2208, 16*384*672) = 4521984
  float* out  = (float*)d_out;

  k_conv1   <<<128, 256, 0, stream>>>(x, w1, g1, b1, h1);
  k_conv2p  <<<512, 384, 0, stream>>>(h1, w2, part);
  k_combine2<<<256, 384, 0, stream>>>(part, g2, b2, h2);
  k_conv3p  <<<3072, 128, 0, stream>>>(h2, w3, part);
  k_combine3<<<384, 384, 0, stream>>>(part, g3, b3, h3);
  k_fcp     <<<384, 256, 0, stream>>>(h3, Wfc, hfcp);
  k_final   <<<1, 128, 0, stream>>>(hfcp, bfc, out);
}

// Round 13
// 146.523 us; speedup vs baseline: 2.5212x; 1.0447x over previous
//
#include <hip/hip_runtime.h>
#include <math.h>

#define DEVINL __device__ __forceinline__

// Deterministic block reduction of two double accumulators.
template<int NWAVES>
DEVINL void block_reduce_2d(double& a, double& b) {
  #pragma unroll
  for (int off = 32; off > 0; off >>= 1) {
    a += __shfl_down(a, off, 64);
    b += __shfl_down(b, off, 64);
  }
  __shared__ double sa[NWAVES], sb[NWAVES];
  const int tid = threadIdx.x;
  const int wid = tid >> 6;
  if ((tid & 63) == 0) { sa[wid] = a; sb[wid] = b; }
  __syncthreads();
  if (tid == 0) {
    double ta = 0.0, tb = 0.0;
    #pragma unroll
    for (int w = 0; w < NWAVES; ++w) { ta += sa[w]; tb += sb[w]; }
    a = ta; b = tb;
  }
}

// ---------------- Layer 1: x(16,1,196,3) * w1(128,1,6,1) s=(2,1) -> h1(16,128,96,3), fused BN+ReLU
__global__ __launch_bounds__(256) void k_conv1(
    const float* __restrict__ x, const float* __restrict__ w1,
    const float* __restrict__ g1, const float* __restrict__ b1,
    float* __restrict__ h1) {
  __shared__ float xlds[9408];          // whole x, 37.6KB
  const int co = blockIdx.x;    // 128
  const int tid = threadIdx.x;  // 256
  {
    float4* xd = (float4*)xlds;
    const float4* xs = (const float4*)x;
    #pragma unroll
    for (int k = 0; k < 10; ++k) {
      const int f = tid + k * 256;
      if (f < 2352) xd[f] = xs[f];
    }
  }
  float wv[6];
  #pragma unroll
  for (int i = 0; i < 6; ++i) wv[i] = w1[co * 6 + i];
  __syncthreads();

  float vals[18];               // 4608 positions / 256 threads
  double s = 0.0, sq = 0.0;
  #pragma unroll
  for (int k = 0; k < 18; ++k) {
    const int p = tid + k * 256;
    const int n = p / 288;
    const int r = p - n * 288;
    const int ho = r / 3;
    const int wo = r - ho * 3;
    const float* xb = xlds + n * 588 + (2 * ho) * 3 + wo;
    float d0 = fabsf(xb[0]  - wv[0]);
    float d1 = fabsf(xb[3]  - wv[1]);
    float d2 = fabsf(xb[6]  - wv[2]);
    float d3 = fabsf(xb[9]  - wv[3]);
    float d4 = fabsf(xb[12] - wv[4]);
    float d5 = fabsf(xb[15] - wv[5]);
    const float v = -(((d0 + d1) + (d2 + d3)) + (d4 + d5));
    vals[k] = v;
    s += (double)v;
    sq += (double)v * (double)v;
  }
  block_reduce_2d<4>(s, sq);
  __shared__ float ssc, ssh;
  if (tid == 0) {
    const double mean = s * (1.0 / 4608.0);
    const double var  = sq * (1.0 / 4608.0) - mean * mean;
    const float rstd = (float)rsqrt(var + 1e-5);
    const float sc = g1[co] * rstd;
    ssc = sc;
    ssh = b1[co] - (float)mean * sc;
  }
  __syncthreads();
  const float sc = ssc, sh = ssh;
  #pragma unroll
  for (int k = 0; k < 18; ++k) {
    const int p = tid + k * 256;
    const int n = p / 288;
    const int r = p - n * 288;
    const int ho = r / 3;
    const int wo = r - ho * 3;
    h1[((n * 128 + co) * 96 + ho) * 3 + wo] = fmaxf(0.f, fmaf(vals[k], sc, sh));
  }
}

// ---------------- Layer 2 partial: h1(16,128,96,3) * w2(256,128,6,1) s=(2,1)
// Grid 1024 = 2 n-halves x 64 co-groups(4) x 8 K-chunks(16 ci). 192 threads, active 184 = 8n x 23hp.
// Thread = 4co x 2po x 3wo, tree-sum. x: 1-ci dbuf LDS [8n][73]. w: one-time LDS, b128 broadcast.
__global__ __launch_bounds__(192) void k_conv2p(
    const float* __restrict__ h1, const float* __restrict__ w2,
    float* __restrict__ part2) {
  __shared__ float wlds[512];           // [ci 16][co 4][8 pad]
  __shared__ float4 xbuf[2][584];       // [8n][73 pad]
  const int bx = blockIdx.x;
  const int kc = bx & 7;
  const int rbx = bx >> 3;
  const int cg = rbx & 63;
  const int nh = rbx >> 6;              // 0 or 1
  const int co0 = cg * 4, ci0 = kc * 16, n0 = nh * 8;
  const int tid = threadIdx.x;          // 192
  #pragma unroll
  for (int f = tid; f < 512; f += 192) {
    const int cil = f >> 5, rem = f & 31, c = rem >> 3, kk = rem & 7;
    wlds[f] = (kk < 6) ? w2[(co0 + c) * 768 + (ci0 + cil) * 6 + kk] : 0.f;
  }
  const bool active = tid < 184;        // 8n x 23hp
  const int n = tid / 23, hp = tid - n * 23;

  // stage slots: 3 float4 per thread per ci (3*192 = 576 = 8n*72 exact)
  int s_lds[3], s_g[3];
  #pragma unroll
  for (int k = 0; k < 3; ++k) {
    const int f = tid + k * 192;
    const int nn = f / 72, j = f - nn * 72;
    s_lds[k] = nn * 73 + j;
    s_g[k]   = (n0 + nn) * 9216 + j;    // + ci*72 at load
  }
  const float4* h1v = (const float4*)h1;

  float acc[4][6];
  #pragma unroll
  for (int c = 0; c < 4; ++c)
    #pragma unroll
    for (int o = 0; o < 6; ++o) acc[c][o] = 0.f;

  float4 r[3];
  #pragma unroll
  for (int k = 0; k < 3; ++k) r[k] = h1v[s_g[k] + ci0 * 72];
  #pragma unroll
  for (int k = 0; k < 3; ++k) xbuf[0][s_lds[k]] = r[k];
  #pragma unroll
  for (int k = 0; k < 3; ++k) r[k] = h1v[s_g[k] + (ci0 + 1) * 72];
  __syncthreads();

  const float4* wl4 = (const float4*)wlds;
  #pragma unroll 1
  for (int ci = 0; ci < 16; ++ci) {
    const float4* cur = xbuf[ci & 1];
    if (ci + 1 < 16) {
      float4* nxt = xbuf[(ci + 1) & 1];
      #pragma unroll
      for (int k = 0; k < 3; ++k) nxt[s_lds[k]] = r[k];
    }
    if (ci + 2 < 16) {
      #pragma unroll
      for (int k = 0; k < 3; ++k) r[k] = h1v[s_g[k] + (ci0 + ci + 2) * 72];
    }
    if (active) {
      const float4* xr = cur + n * 73 + hp * 3;
      float xf[24];
      #pragma unroll
      for (int t = 0; t < 6; ++t) {
        const float4 q = xr[t];
        xf[4 * t + 0] = q.x; xf[4 * t + 1] = q.y; xf[4 * t + 2] = q.z; xf[4 * t + 3] = q.w;
      }
      #pragma unroll
      for (int c = 0; c < 4; ++c) {
        const float4 wa = wl4[(ci * 4 + c) * 2];        // wave-uniform broadcast
        const float4 wb = wl4[(ci * 4 + c) * 2 + 1];
        const float wv[6] = {wa.x, wa.y, wa.z, wa.w, wb.x, wb.y};
        #pragma unroll
        for (int po = 0; po < 2; ++po)
          #pragma unroll
          for (int wo = 0; wo < 3; ++wo) {
            float d0 = fabsf(xf[(2 * po + 0) * 3 + wo] - wv[0]);
            float d1 = fabsf(xf[(2 * po + 1) * 3 + wo] - wv[1]);
            float d2 = fabsf(xf[(2 * po + 2) * 3 + wo] - wv[2]);
            float d3 = fabsf(xf[(2 * po + 3) * 3 + wo] - wv[3]);
            float d4 = fabsf(xf[(2 * po + 4) * 3 + wo] - wv[4]);
            float d5 = fabsf(xf[(2 * po + 5) * 3 + wo] - wv[5]);
            acc[c][po * 3 + wo] += ((d0 + d1) + (d2 + d3)) + (d4 + d5);
          }
      }
    }
    __syncthreads();
  }
  if (active) {
    #pragma unroll
    for (int c = 0; c < 4; ++c)
      #pragma unroll
      for (int po = 0; po < 2; ++po)
        #pragma unroll
        for (int wo = 0; wo < 3; ++wo) {
          const int p = (n0 + n) * 138 + (2 * hp + po) * 3 + wo;
          part2[(size_t)(kc * 256 + co0 + c) * 2208 + p] = acc[c][po * 3 + wo];
        }
  }
}

// ---------------- Layer 2 combine: sum 8 K-partials, BN stats + apply -> h2(16,256,46,3)
__global__ __launch_bounds__(384) void k_combine2(
    const float* __restrict__ part2, const float* __restrict__ g2,
    const float* __restrict__ b2, float* __restrict__ h2) {
  const int co = blockIdx.x;    // 256
  const int tid = threadIdx.x;  // 384, active 368, 6 pos each
  const bool active = tid < 368;
  float v[6];
  double s = 0.0, sq = 0.0;
  #pragma unroll
  for (int k = 0; k < 6; ++k) {
    float sum = 0.f;
    if (active) {
      const int p = tid + k * 368;
      #pragma unroll
      for (int kc = 0; kc < 8; ++kc)
        sum += part2[(size_t)(kc * 256 + co) * 2208 + p];
    }
    const float val = -sum;
    v[k] = val;
    if (active) { s += (double)val; sq += (double)val * (double)val; }
  }
  block_reduce_2d<6>(s, sq);
  __shared__ float ssc, ssh;
  if (tid == 0) {
    const double mean = s * (1.0 / 2208.0);
    const double var  = sq * (1.0 / 2208.0) - mean * mean;
    const float rstd = (float)rsqrt(var + 1e-5);
    const float sc = g2[co] * rstd;
    ssc = sc;
    ssh = b2[co] - (float)mean * sc;
  }
  __syncthreads();
  if (active) {
    const float sc = ssc, sh = ssh;
    #pragma unroll
    for (int k = 0; k < 6; ++k) {
      const int p = tid + k * 368;
      const int n = p / 138, rem = p - n * 138;
      h2[n * 35328 + co * 138 + rem] = fmaxf(0.f, fmaf(v[k], sc, sh));
    }
  }
}

// ---------------- Layer 3 partial: h2(16,256,46,3) * w3(384,256,6,2) s=(2,1)
// Grid 6144 = 4 n-quarters x 96 co-groups(4) x 16 K-chunks(16 ci). 128 threads, active 112
// = 4n x 7hot x 4cq; thread = 1co x 3ho x 2wo from a 30-float window (72 taps per w-fetch).
// Tree-sum. x: 1-ci dbuf LDS [4n][71 pad] (4.5KB). w: one-time LDS (3KB), 3x b128 broadcast.
__global__ __launch_bounds__(128) void k_conv3p(
    const float* __restrict__ h2, const float* __restrict__ w3,
    float* __restrict__ part3) {
  __shared__ float wlds[768];           // [ci 16][co 4][12]
  __shared__ float2 xbuf[2][284];       // [4n][71 pad]
  const int bx = blockIdx.x;
  const int kc = bx & 15;
  const int rbx = bx >> 4;
  const int cg = rbx % 96;
  const int nh = rbx / 96;              // 0..3
  const int co0 = cg * 4, ci0 = kc * 16, n0 = nh * 4;
  const int tid = threadIdx.x;          // 128
  #pragma unroll
  for (int f = tid; f < 768; f += 128) {
    const int cil = f / 48, rem = f - cil * 48, c = rem / 12, kk = rem - c * 12;
    wlds[f] = w3[(co0 + c) * 3072 + (ci0 + cil) * 12 + kk];
  }
  const bool active = tid < 112;        // 4n x 7hot x 4cq
  const int n = tid / 28;               // 0..3
  const int rem28 = tid - n * 28;
  const int hot = rem28 >> 2;           // 0..6
  const int cq = rem28 & 3;             // co within group

  // stage slots: 3 float2 per thread per ci (2*128 + 20 = 276 = 4n*69)
  int s_lds[3], s_g[3];
  const bool v3 = tid < 20;
  #pragma unroll
  for (int k = 0; k < 3; ++k) {
    const int f = tid + k * 128;
    const int nn = f / 69, j = f - nn * 69;
    s_lds[k] = nn * 71 + j;
    s_g[k]   = (n0 + nn) * 17664 + j;   // + ci*69 at load
  }
  const float2* h2v = (const float2*)h2;

  float acc[3][2];
  #pragma unroll
  for (int h = 0; h < 3; ++h) { acc[h][0] = 0.f; acc[h][1] = 0.f; }

  float2 r[3];
  #pragma unroll
  for (int k = 0; k < 2; ++k) r[k] = h2v[s_g[k] + ci0 * 69];
  if (v3) r[2] = h2v[s_g[2] + ci0 * 69];
  #pragma unroll
  for (int k = 0; k < 2; ++k) xbuf[0][s_lds[k]] = r[k];
  if (v3) xbuf[0][s_lds[2]] = r[2];
  #pragma unroll
  for (int k = 0; k < 2; ++k) r[k] = h2v[s_g[k] + (ci0 + 1) * 69];
  if (v3) r[2] = h2v[s_g[2] + (ci0 + 1) * 69];
  __syncthreads();

  const float4* wl4 = (const float4*)wlds;
  #pragma unroll 1
  for (int ci = 0; ci < 16; ++ci) {
    const float2* cur = xbuf[ci & 1];
    if (ci + 1 < 16) {
      float2* nxt = xbuf[(ci + 1) & 1];
      #pragma unroll
      for (int k = 0; k < 2; ++k) nxt[s_lds[k]] = r[k];
      if (v3) nxt[s_lds[2]] = r[2];
    }
    if (ci + 2 < 16) {
      #pragma unroll
      for (int k = 0; k < 2; ++k) r[k] = h2v[s_g[k] + (ci0 + ci + 2) * 69];
      if (v3) r[2] = h2v[s_g[2] + (ci0 + ci + 2) * 69];
    }
    if (active) {
      // 10-row window rows 6hot..6hot+9 = 30 floats, shared by 3 ho
      float xf[30];
      const float2* xr = cur + n * 71 + 9 * hot;
      #pragma unroll
      for (int t = 0; t < 15; ++t) {
        const float2 q = xr[t];
        xf[2 * t + 0] = q.x; xf[2 * t + 1] = q.y;
      }
      const float4 w0 = wl4[(ci * 4 + cq) * 3];         // broadcast, 1 fetch / 72 taps
      const float4 w1 = wl4[(ci * 4 + cq) * 3 + 1];
      const float4 w2q = wl4[(ci * 4 + cq) * 3 + 2];
      const float wv[12] = {w0.x, w0.y, w0.z, w0.w, w1.x, w1.y,
                            w1.z, w1.w, w2q.x, w2q.y, w2q.z, w2q.w};
      #pragma unroll
      for (int h = 0; h < 3; ++h)
        #pragma unroll
        for (int wo = 0; wo < 2; ++wo) {
          float d[12];
          #pragma unroll
          for (int i = 0; i < 6; ++i) {
            d[2 * i]     = fabsf(xf[(2 * h + i) * 3 + wo]     - wv[2 * i]);
            d[2 * i + 1] = fabsf(xf[(2 * h + i) * 3 + wo + 1] - wv[2 * i + 1]);
          }
          const float s0 = (d[0] + d[1]) + (d[2] + d[3]);
          const float s1 = (d[4] + d[5]) + (d[6] + d[7]);
          const float s2 = (d[8] + d[9]) + (d[10] + d[11]);
          acc[h][wo] += (s0 + s1) + s2;
        }
    }
    __syncthreads();
  }
  if (active) {
    #pragma unroll
    for (int h = 0; h < 3; ++h) {
      const int ho = 3 * hot + h;       // 0..20
      #pragma unroll
      for (int wo = 0; wo < 2; ++wo) {
        const int p = (n0 + n) * 42 + ho * 2 + wo;
        part3[(size_t)(kc * 384 + co0 + cq) * 672 + p] = acc[h][wo];
      }
    }
  }
}

// ---------------- Layer 3 combine: sum 16 K-partials, BN stats + apply -> h3(16,384,21,2)
__global__ __launch_bounds__(384) void k_combine3(
    const float* __restrict__ part3, const float* __restrict__ g3,
    const float* __restrict__ b3, float* __restrict__ h3) {
  const int co = blockIdx.x;    // 384
  const int tid = threadIdx.x;  // 384, active 336, 2 pos each
  const bool active = tid < 336;
  float v[2];
  double s = 0.0, sq = 0.0;
  #pragma unroll
  for (int k = 0; k < 2; ++k) {
    float sum = 0.f;
    if (active) {
      const int p = tid + k * 336;
      #pragma unroll
      for (int kc = 0; kc < 16; ++kc)
        sum += part3[(size_t)(kc * 384 + co) * 672 + p];
    }
    const float val = -sum;
    v[k] = val;
    if (active) { s += (double)val; sq += (double)val * (double)val; }
  }
  block_reduce_2d<6>(s, sq);
  __shared__ float ssc, ssh;
  if (tid == 0) {
    const double mean = s * (1.0 / 672.0);
    const double var  = sq * (1.0 / 672.0) - mean * mean;
    const float rstd = (float)rsqrt(var + 1e-5);
    const float sc = g3[co] * rstd;
    ssc = sc;
    ssh = b3[co] - (float)mean * sc;
  }
  __syncthreads();
  if (active) {
    const float sc = ssc, sh = ssh;
    #pragma unroll
    for (int k = 0; k < 2; ++k) {
      const int p = tid + k * 336;
      const int n = p / 42, rem = p - n * 42;
      h3[n * 16128 + co * 42 + rem] = fmaxf(0.f, fmaf(v[k], sc, sh));
    }
  }
}

// ---------------- FC partial: h3(16,16128) @ Wfc(6,16128)^T, K split 4 ways
__global__ __launch_bounds__(256) void k_fcp(
    const float* __restrict__ h3, const float* __restrict__ Wfc,
    float* __restrict__ hfcp) {
  const int bx = blockIdx.x;    // 384 = 96 pairs x 4
  const int pair = bx >> 2, q = bx & 3;
  const int n = pair / 6, o = pair - n * 6;
  const float4* xr = (const float4*)(h3 + n * 16128) + q * 1008;
  const float4* wr = (const float4*)(Wfc + o * 16128) + q * 1008;
  float sacc = 0.f;
  for (int k = threadIdx.x; k < 1008; k += 256) {
    const float4 xv = xr[k];
    const float4 wv = wr[k];
    sacc += xv.x * wv.x + xv.y * wv.y + xv.z * wv.z + xv.w * wv.w;
  }
  double d = (double)sacc, dummy = 0.0;
  block_reduce_2d<4>(d, dummy);
  if (threadIdx.x == 0) hfcp[bx] = (float)d;
}

// ---------------- Final: sum FC partials + bias, LayerNorm over 96, per-row L2 norm -> out(16,6)
__global__ __launch_bounds__(128) void k_final(
    const float* __restrict__ hfcp, const float* __restrict__ bfc,
    float* __restrict__ out) {
  __shared__ float ys[96];
  __shared__ float params[2];
  const int tid = threadIdx.x;
  float v = 0.f;
  if (tid < 96) {
    v = hfcp[tid * 4 + 0] + hfcp[tid * 4 + 1] + hfcp[tid * 4 + 2] + hfcp[tid * 4 + 3]
        + bfc[tid % 6];
    ys[tid] = v;
  }
  __syncthreads();
  if (tid == 0) {
    double s = 0.0, sq = 0.0;
    for (int i = 0; i < 96; ++i) { const double t = (double)ys[i]; s += t; sq += t * t; }
    const double mu = s / 96.0;
    const double var = sq / 96.0 - mu * mu;
    params[0] = (float)mu;
    params[1] = (float)rsqrt(var + 1e-5);
  }
  __syncthreads();
  const float y = (v - params[0]) * params[1];
  __syncthreads();
  if (tid < 96) ys[tid] = y;
  __syncthreads();
  if (tid < 96) {
    const int n = tid / 6;
    float ss = 0.f;
    #pragma unroll
    for (int k = 0; k < 6; ++k) { const float t = ys[n * 6 + k]; ss += t * t; }
    const float norm = sqrtf(ss);
    out[tid] = y / fmaxf(norm, 1e-12f);
  }
}

extern "C" void kernel_launch(void* const* d_in, const int* in_sizes, int n_in,
                              void* d_out, int out_size, void* d_ws, size_t ws_size,
                              hipStream_t stream) {
  const float* x   = (const float*)d_in[0];
  const float* w1  = (const float*)d_in[1];
  const float* g1  = (const float*)d_in[2];
  const float* b1  = (const float*)d_in[3];
  const float* w2  = (const float*)d_in[4];
  const float* g2  = (const float*)d_in[5];
  const float* b2  = (const float*)d_in[6];
  const float* w3  = (const float*)d_in[7];
  const float* g3  = (const float*)d_in[8];
  const float* b3  = (const float*)d_in[9];
  const float* Wfc = (const float*)d_in[10];
  const float* bfc = (const float*)d_in[11];

  float* ws   = (float*)d_ws;
  float* h1   = ws;                 // 589824
  float* h2   = h1 + 589824;        // 565248
  float* h3   = h2 + 565248;        // 258048
  float* hfcp = h3 + 258048;        // 384
  float* part = hfcp + 384;         // max(8*256*2208, 16*384*672) = 4521984
  float* out  = (float*)d_out;

  k_conv1   <<<128, 256, 0, stream>>>(x, w1, g1, b1, h1);
  k_conv2p  <<<1024, 192, 0, stream>>>(h1, w2, part);
  k_combine2<<<256, 384, 0, stream>>>(part, g2, b2, h2);
  k_conv3p  <<<6144, 128, 0, stream>>>(h2, w3, part);
  k_combine3<<<384, 384, 0, stream>>>(part, g3, b3, h3);
  k_fcp     <<<384, 256, 0, stream>>>(h3, Wfc, hfcp);
  k_final   <<<1, 128, 0, stream>>>(hfcp, bfc, out);
}

// Round 14
// 127.240 us; speedup vs baseline: 2.9033x; 1.1515x over previous
//
#include <hip/hip_runtime.h>
#include <math.h>

#define DEVINL __device__ __forceinline__

// Forced VOP3 abs-modifier add: dst = |a| + |b| in ONE v_add_f32.
DEVINL float absadd(float a, float b) {
  float t;
  asm("v_add_f32 %0, |%1|, |%2|" : "=v"(t) : "v"(a), "v"(b));
  return t;
}

// Deterministic block reduction of two double accumulators.
template<int NWAVES>
DEVINL void block_reduce_2d(double& a, double& b) {
  #pragma unroll
  for (int off = 32; off > 0; off >>= 1) {
    a += __shfl_down(a, off, 64);
    b += __shfl_down(b, off, 64);
  }
  __shared__ double sa[NWAVES], sb[NWAVES];
  const int tid = threadIdx.x;
  const int wid = tid >> 6;
  if ((tid & 63) == 0) { sa[wid] = a; sb[wid] = b; }
  __syncthreads();
  if (tid == 0) {
    double ta = 0.0, tb = 0.0;
    #pragma unroll
    for (int w = 0; w < NWAVES; ++w) { ta += sa[w]; tb += sb[w]; }
    a = ta; b = tb;
  }
}

// ---------------- Layer 1: x(16,1,196,3) * w1(128,1,6,1) s=(2,1) -> h1(16,128,96,3), fused BN+ReLU
__global__ __launch_bounds__(256) void k_conv1(
    const float* __restrict__ x, const float* __restrict__ w1,
    const float* __restrict__ g1, const float* __restrict__ b1,
    float* __restrict__ h1) {
  __shared__ float xlds[9408];          // whole x, 37.6KB
  const int co = blockIdx.x;    // 128
  const int tid = threadIdx.x;  // 256
  {
    float4* xd = (float4*)xlds;
    const float4* xs = (const float4*)x;
    #pragma unroll
    for (int k = 0; k < 10; ++k) {
      const int f = tid + k * 256;
      if (f < 2352) xd[f] = xs[f];
    }
  }
  float wv[6];
  #pragma unroll
  for (int i = 0; i < 6; ++i) wv[i] = w1[co * 6 + i];
  __syncthreads();

  float vals[18];               // 4608 positions / 256 threads
  double s = 0.0, sq = 0.0;
  #pragma unroll
  for (int k = 0; k < 18; ++k) {
    const int p = tid + k * 256;
    const int n = p / 288;
    const int r = p - n * 288;
    const int ho = r / 3;
    const int wo = r - ho * 3;
    const float* xb = xlds + n * 588 + (2 * ho) * 3 + wo;
    float e0 = xb[0]  - wv[0];
    float e1 = xb[3]  - wv[1];
    float e2 = xb[6]  - wv[2];
    float e3 = xb[9]  - wv[3];
    float e4 = xb[12] - wv[4];
    float e5 = xb[15] - wv[5];
    const float t0 = absadd(e0, e1);
    const float t1 = absadd(e2, e3);
    const float t2 = absadd(e4, e5);
    const float v = -((t0 + t1) + t2);
    vals[k] = v;
    s += (double)v;
    sq += (double)v * (double)v;
  }
  block_reduce_2d<4>(s, sq);
  __shared__ float ssc, ssh;
  if (tid == 0) {
    const double mean = s * (1.0 / 4608.0);
    const double var  = sq * (1.0 / 4608.0) - mean * mean;
    const float rstd = (float)rsqrt(var + 1e-5);
    const float sc = g1[co] * rstd;
    ssc = sc;
    ssh = b1[co] - (float)mean * sc;
  }
  __syncthreads();
  const float sc = ssc, sh = ssh;
  #pragma unroll
  for (int k = 0; k < 18; ++k) {
    const int p = tid + k * 256;
    const int n = p / 288;
    const int r = p - n * 288;
    const int ho = r / 3;
    const int wo = r - ho * 3;
    h1[((n * 128 + co) * 96 + ho) * 3 + wo] = fmaxf(0.f, fmaf(vals[k], sc, sh));
  }
}

// ---------------- Layer 2 partial: h1(16,128,96,3) * w2(256,128,6,1) s=(2,1)
// Grid 1024 = 2 n-halves x 64 co-groups(4) x 8 K-chunks(16 ci). 192 threads, active 184 = 8n x 23hp.
// Thread = 4co x 2po x 3wo, asm-abs tree (2 inst/tap). x: 1-ci dbuf LDS [8n][73]. w: LDS b128 broadcast.
__global__ __launch_bounds__(192) void k_conv2p(
    const float* __restrict__ h1, const float* __restrict__ w2,
    float* __restrict__ part2) {
  __shared__ float wlds[512];           // [ci 16][co 4][8 pad]
  __shared__ float4 xbuf[2][584];       // [8n][73 pad]
  const int bx = blockIdx.x;
  const int kc = bx & 7;
  const int rbx = bx >> 3;
  const int cg = rbx & 63;
  const int nh = rbx >> 6;              // 0 or 1
  const int co0 = cg * 4, ci0 = kc * 16, n0 = nh * 8;
  const int tid = threadIdx.x;          // 192
  #pragma unroll
  for (int f = tid; f < 512; f += 192) {
    const int cil = f >> 5, rem = f & 31, c = rem >> 3, kk = rem & 7;
    wlds[f] = (kk < 6) ? w2[(co0 + c) * 768 + (ci0 + cil) * 6 + kk] : 0.f;
  }
  const bool active = tid < 184;        // 8n x 23hp
  const int n = tid / 23, hp = tid - n * 23;

  // stage slots: 3 float4 per thread per ci (3*192 = 576 = 8n*72 exact)
  int s_lds[3], s_g[3];
  #pragma unroll
  for (int k = 0; k < 3; ++k) {
    const int f = tid + k * 192;
    const int nn = f / 72, j = f - nn * 72;
    s_lds[k] = nn * 73 + j;
    s_g[k]   = (n0 + nn) * 9216 + j;    // + ci*72 at load
  }
  const float4* h1v = (const float4*)h1;

  float acc[4][6];
  #pragma unroll
  for (int c = 0; c < 4; ++c)
    #pragma unroll
    for (int o = 0; o < 6; ++o) acc[c][o] = 0.f;

  float4 r[3];
  #pragma unroll
  for (int k = 0; k < 3; ++k) r[k] = h1v[s_g[k] + ci0 * 72];
  #pragma unroll
  for (int k = 0; k < 3; ++k) xbuf[0][s_lds[k]] = r[k];
  #pragma unroll
  for (int k = 0; k < 3; ++k) r[k] = h1v[s_g[k] + (ci0 + 1) * 72];
  __syncthreads();

  const float4* wl4 = (const float4*)wlds;
  #pragma unroll 1
  for (int ci = 0; ci < 16; ++ci) {
    const float4* cur = xbuf[ci & 1];
    if (ci + 1 < 16) {
      float4* nxt = xbuf[(ci + 1) & 1];
      #pragma unroll
      for (int k = 0; k < 3; ++k) nxt[s_lds[k]] = r[k];
    }
    if (ci + 2 < 16) {
      #pragma unroll
      for (int k = 0; k < 3; ++k) r[k] = h1v[s_g[k] + (ci0 + ci + 2) * 72];
    }
    if (active) {
      const float4* xr = cur + n * 73 + hp * 3;
      float xf[24];
      #pragma unroll
      for (int t = 0; t < 6; ++t) {
        const float4 q = xr[t];
        xf[4 * t + 0] = q.x; xf[4 * t + 1] = q.y; xf[4 * t + 2] = q.z; xf[4 * t + 3] = q.w;
      }
      #pragma unroll
      for (int c = 0; c < 4; ++c) {
        const float4 wa = wl4[(ci * 4 + c) * 2];        // wave-uniform broadcast
        const float4 wb = wl4[(ci * 4 + c) * 2 + 1];
        const float wv[6] = {wa.x, wa.y, wa.z, wa.w, wb.x, wb.y};
        #pragma unroll
        for (int po = 0; po < 2; ++po)
          #pragma unroll
          for (int wo = 0; wo < 3; ++wo) {
            float e0 = xf[(2 * po + 0) * 3 + wo] - wv[0];
            float e1 = xf[(2 * po + 1) * 3 + wo] - wv[1];
            float e2 = xf[(2 * po + 2) * 3 + wo] - wv[2];
            float e3 = xf[(2 * po + 3) * 3 + wo] - wv[3];
            float e4 = xf[(2 * po + 4) * 3 + wo] - wv[4];
            float e5 = xf[(2 * po + 5) * 3 + wo] - wv[5];
            const float t0 = absadd(e0, e1);
            const float t1 = absadd(e2, e3);
            const float t2 = absadd(e4, e5);
            acc[c][po * 3 + wo] += (t0 + t1) + t2;
          }
      }
    }
    __syncthreads();
  }
  if (active) {
    #pragma unroll
    for (int c = 0; c < 4; ++c)
      #pragma unroll
      for (int po = 0; po < 2; ++po)
        #pragma unroll
        for (int wo = 0; wo < 3; ++wo) {
          const int p = (n0 + n) * 138 + (2 * hp + po) * 3 + wo;
          part2[(size_t)(kc * 256 + co0 + c) * 2208 + p] = acc[c][po * 3 + wo];
        }
  }
}

// ---------------- Layer 2 combine: sum 8 K-partials, BN stats + apply -> h2(16,256,46,3)
__global__ __launch_bounds__(384) void k_combine2(
    const float* __restrict__ part2, const float* __restrict__ g2,
    const float* __restrict__ b2, float* __restrict__ h2) {
  const int co = blockIdx.x;    // 256
  const int tid = threadIdx.x;  // 384, active 368, 6 pos each
  const bool active = tid < 368;
  float v[6];
  double s = 0.0, sq = 0.0;
  #pragma unroll
  for (int k = 0; k < 6; ++k) {
    float sum = 0.f;
    if (active) {
      const int p = tid + k * 368;
      #pragma unroll
      for (int kc = 0; kc < 8; ++kc)
        sum += part2[(size_t)(kc * 256 + co) * 2208 + p];
    }
    const float val = -sum;
    v[k] = val;
    if (active) { s += (double)val; sq += (double)val * (double)val; }
  }
  block_reduce_2d<6>(s, sq);
  __shared__ float ssc, ssh;
  if (tid == 0) {
    const double mean = s * (1.0 / 2208.0);
    const double var  = sq * (1.0 / 2208.0) - mean * mean;
    const float rstd = (float)rsqrt(var + 1e-5);
    const float sc = g2[co] * rstd;
    ssc = sc;
    ssh = b2[co] - (float)mean * sc;
  }
  __syncthreads();
  if (active) {
    const float sc = ssc, sh = ssh;
    #pragma unroll
    for (int k = 0; k < 6; ++k) {
      const int p = tid + k * 368;
      const int n = p / 138, rem = p - n * 138;
      h2[n * 35328 + co * 138 + rem] = fmaxf(0.f, fmaf(v[k], sc, sh));
    }
  }
}

// ---------------- Layer 3 partial: h2(16,256,46,3) * w3(384,256,6,2) s=(2,1)
// Grid 6144 = 4 n-quarters x 96 co-groups(4) x 16 K-chunks(16 ci). 128 threads, active 112
// = 4n x 7hot x 4cq; thread = 1co x 3ho x 2wo from a 30-float window (72 taps per w-fetch).
// asm-abs tree (2 inst/tap). x: 1-ci dbuf LDS [4n][71 pad]. w: one-time LDS, 3x b128 broadcast.
__global__ __launch_bounds__(128) void k_conv3p(
    const float* __restrict__ h2, const float* __restrict__ w3,
    float* __restrict__ part3) {
  __shared__ float wlds[768];           // [ci 16][co 4][12]
  __shared__ float2 xbuf[2][284];       // [4n][71 pad]
  const int bx = blockIdx.x;
  const int kc = bx & 15;
  const int rbx = bx >> 4;
  const int cg = rbx % 96;
  const int nh = rbx / 96;              // 0..3
  const int co0 = cg * 4, ci0 = kc * 16, n0 = nh * 4;
  const int tid = threadIdx.x;          // 128
  #pragma unroll
  for (int f = tid; f < 768; f += 128) {
    const int cil = f / 48, rem = f - cil * 48, c = rem / 12, kk = rem - c * 12;
    wlds[f] = w3[(co0 + c) * 3072 + (ci0 + cil) * 12 + kk];
  }
  const bool active = tid < 112;        // 4n x 7hot x 4cq
  const int n = tid / 28;               // 0..3
  const int rem28 = tid - n * 28;
  const int hot = rem28 >> 2;           // 0..6
  const int cq = rem28 & 3;             // co within group

  // stage slots: 3 float2 per thread per ci (2*128 + 20 = 276 = 4n*69)
  int s_lds[3], s_g[3];
  const bool v3 = tid < 20;
  #pragma unroll
  for (int k = 0; k < 3; ++k) {
    const int f = tid + k * 128;
    const int nn = f / 69, j = f - nn * 69;
    s_lds[k] = nn * 71 + j;
    s_g[k]   = (n0 + nn) * 17664 + j;   // + ci*69 at load
  }
  const float2* h2v = (const float2*)h2;

  float acc[3][2];
  #pragma unroll
  for (int h = 0; h < 3; ++h) { acc[h][0] = 0.f; acc[h][1] = 0.f; }

  float2 r[3];
  #pragma unroll
  for (int k = 0; k < 2; ++k) r[k] = h2v[s_g[k] + ci0 * 69];
  if (v3) r[2] = h2v[s_g[2] + ci0 * 69];
  #pragma unroll
  for (int k = 0; k < 2; ++k) xbuf[0][s_lds[k]] = r[k];
  if (v3) xbuf[0][s_lds[2]] = r[2];
  #pragma unroll
  for (int k = 0; k < 2; ++k) r[k] = h2v[s_g[k] + (ci0 + 1) * 69];
  if (v3) r[2] = h2v[s_g[2] + (ci0 + 1) * 69];
  __syncthreads();

  const float4* wl4 = (const float4*)wlds;
  #pragma unroll 1
  for (int ci = 0; ci < 16; ++ci) {
    const float2* cur = xbuf[ci & 1];
    if (ci + 1 < 16) {
      float2* nxt = xbuf[(ci + 1) & 1];
      #pragma unroll
      for (int k = 0; k < 2; ++k) nxt[s_lds[k]] = r[k];
      if (v3) nxt[s_lds[2]] = r[2];
    }
    if (ci + 2 < 16) {
      #pragma unroll
      for (int k = 0; k < 2; ++k) r[k] = h2v[s_g[k] + (ci0 + ci + 2) * 69];
      if (v3) r[2] = h2v[s_g[2] + (ci0 + ci + 2) * 69];
    }
    if (active) {
      // 10-row window rows 6hot..6hot+9 = 30 floats, shared by 3 ho
      float xf[30];
      const float2* xr = cur + n * 71 + 9 * hot;
      #pragma unroll
      for (int t = 0; t < 15; ++t) {
        const float2 q = xr[t];
        xf[2 * t + 0] = q.x; xf[2 * t + 1] = q.y;
      }
      const float4 w0 = wl4[(ci * 4 + cq) * 3];         // broadcast, 1 fetch / 72 taps
      const float4 w1 = wl4[(ci * 4 + cq) * 3 + 1];
      const float4 w2q = wl4[(ci * 4 + cq) * 3 + 2];
      const float wv[12] = {w0.x, w0.y, w0.z, w0.w, w1.x, w1.y,
                            w1.z, w1.w, w2q.x, w2q.y, w2q.z, w2q.w};
      #pragma unroll
      for (int h = 0; h < 3; ++h)
        #pragma unroll
        for (int wo = 0; wo < 2; ++wo) {
          float e0  = xf[(2 * h + 0) * 3 + wo]     - wv[0];
          float e1  = xf[(2 * h + 0) * 3 + wo + 1] - wv[1];
          float e2  = xf[(2 * h + 1) * 3 + wo]     - wv[2];
          float e3  = xf[(2 * h + 1) * 3 + wo + 1] - wv[3];
          float e4  = xf[(2 * h + 2) * 3 + wo]     - wv[4];
          float e5  = xf[(2 * h + 2) * 3 + wo + 1] - wv[5];
          float e6  = xf[(2 * h + 3) * 3 + wo]     - wv[6];
          float e7  = xf[(2 * h + 3) * 3 + wo + 1] - wv[7];
          float e8  = xf[(2 * h + 4) * 3 + wo]     - wv[8];
          float e9  = xf[(2 * h + 4) * 3 + wo + 1] - wv[9];
          float e10 = xf[(2 * h + 5) * 3 + wo]     - wv[10];
          float e11 = xf[(2 * h + 5) * 3 + wo + 1] - wv[11];
          const float t0 = absadd(e0, e1);
          const float t1 = absadd(e2, e3);
          const float t2 = absadd(e4, e5);
          const float t3 = absadd(e6, e7);
          const float t4 = absadd(e8, e9);
          const float t5 = absadd(e10, e11);
          acc[h][wo] += ((t0 + t1) + (t2 + t3)) + (t4 + t5);
        }
    }
    __syncthreads();
  }
  if (active) {
    #pragma unroll
    for (int h = 0; h < 3; ++h) {
      const int ho = 3 * hot + h;       // 0..20
      #pragma unroll
      for (int wo = 0; wo < 2; ++wo) {
        const int p = (n0 + n) * 42 + ho * 2 + wo;
        part3[(size_t)(kc * 384 + co0 + cq) * 672 + p] = acc[h][wo];
      }
    }
  }
}

// ---------------- Layer 3 combine: sum 16 K-partials, BN stats + apply -> h3(16,384,21,2)
__global__ __launch_bounds__(384) void k_combine3(
    const float* __restrict__ part3, const float* __restrict__ g3,
    const float* __restrict__ b3, float* __restrict__ h3) {
  const int co = blockIdx.x;    // 384
  const int tid = threadIdx.x;  // 384, active 336, 2 pos each
  const bool active = tid < 336;
  float v[2];
  double s = 0.0, sq = 0.0;
  #pragma unroll
  for (int k = 0; k < 2; ++k) {
    float sum = 0.f;
    if (active) {
      const int p = tid + k * 336;
      #pragma unroll
      for (int kc = 0; kc < 16; ++kc)
        sum += part3[(size_t)(kc * 384 + co) * 672 + p];
    }
    const float val = -sum;
    v[k] = val;
    if (active) { s += (double)val; sq += (double)val * (double)val; }
  }
  block_reduce_2d<6>(s, sq);
  __shared__ float ssc, ssh;
  if (tid == 0) {
    const double mean = s * (1.0 / 672.0);
    const double var  = sq * (1.0 / 672.0) - mean * mean;
    const float rstd = (float)rsqrt(var + 1e-5);
    const float sc = g3[co] * rstd;
    ssc = sc;
    ssh = b3[co] - (float)mean * sc;
  }
  __syncthreads();
  if (active) {
    const float sc = ssc, sh = ssh;
    #pragma unroll
    for (int k = 0; k < 2; ++k) {
      const int p = tid + k * 336;
      const int n = p / 42, rem = p - n * 42;
      h3[n * 16128 + co * 42 + rem] = fmaxf(0.f, fmaf(v[k], sc, sh));
    }
  }
}

// ---------------- FC partial: h3(16,16128) @ Wfc(6,16128)^T, K split 4 ways
__global__ __launch_bounds__(256) void k_fcp(
    const float* __restrict__ h3, const float* __restrict__ Wfc,
    float* __restrict__ hfcp) {
  const int bx = blockIdx.x;    // 384 = 96 pairs x 4
  const int pair = bx >> 2, q = bx & 3;
  const int n = pair / 6, o = pair - n * 6;
  const float4* xr = (const float4*)(h3 + n * 16128) + q * 1008;
  const float4* wr = (const float4*)(Wfc + o * 16128) + q * 1008;
  float sacc = 0.f;
  for (int k = threadIdx.x; k < 1008; k += 256) {
    const float4 xv = xr[k];
    const float4 wv = wr[k];
    sacc += xv.x * wv.x + xv.y * wv.y + xv.z * wv.z + xv.w * wv.w;
  }
  double d = (double)sacc, dummy = 0.0;
  block_reduce_2d<4>(d, dummy);
  if (threadIdx.x == 0) hfcp[bx] = (float)d;
}

// ---------------- Final: sum FC partials + bias, LayerNorm over 96, per-row L2 norm -> out(16,6)
__global__ __launch_bounds__(128) void k_final(
    const float* __restrict__ hfcp, const float* __restrict__ bfc,
    float* __restrict__ out) {
  __shared__ float ys[96];
  __shared__ float params[2];
  const int tid = threadIdx.x;
  float v = 0.f;
  if (tid < 96) {
    v = hfcp[tid * 4 + 0] + hfcp[tid * 4 + 1] + hfcp[tid * 4 + 2] + hfcp[tid * 4 + 3]
        + bfc[tid % 6];
    ys[tid] = v;
  }
  __syncthreads();
  if (tid == 0) {
    double s = 0.0, sq = 0.0;
    for (int i = 0; i < 96; ++i) { const double t = (double)ys[i]; s += t; sq += t * t; }
    const double mu = s / 96.0;
    const double var = sq / 96.0 - mu * mu;
    params[0] = (float)mu;
    params[1] = (float)rsqrt(var + 1e-5);
  }
  __syncthreads();
  const float y = (v - params[0]) * params[1];
  __syncthreads();
  if (tid < 96) ys[tid] = y;
  __syncthreads();
  if (tid < 96) {
    const int n = tid / 6;
    float ss = 0.f;
    #pragma unroll
    for (int k = 0; k < 6; ++k) { const float t = ys[n * 6 + k]; ss += t * t; }
    const float norm = sqrtf(ss);
    out[tid] = y / fmaxf(norm, 1e-12f);
  }
}

extern "C" void kernel_launch(void* const* d_in, const int* in_sizes, int n_in,
                              void* d_out, int out_size, void* d_ws, size_t ws_size,
                              hipStream_t stream) {
  const float* x   = (const float*)d_in[0];
  const float* w1  = (const float*)d_in[1];
  const float* g1  = (const float*)d_in[2];
  const float* b1  = (const float*)d_in[3];
  const float* w2  = (const float*)d_in[4];
  const float* g2  = (const float*)d_in[5];
  const float* b2  = (const float*)d_in[6];
  const float* w3  = (const float*)d_in[7];
  const float* g3  = (const float*)d_in[8];
  const float* b3  = (const float*)d_in[9];
  const float* Wfc = (const float*)d_in[10];
  const float* bfc = (const float*)d_in[11];

  float* ws   = (float*)d_ws;
  float* h1   = ws;                 // 589824
  float* h2   = h1 + 589824;        // 565248
  float* h3   = h2 + 565248;        // 258048
  float* hfcp = h3 + 258048;        // 384
  float* part = hfcp + 384;         // max(8*256*2208, 16*384*672) = 4521984
  float* out  = (float*)d_out;

  k_conv1   <<<128, 256, 0, stream>>>(x, w1, g1, b1, h1);
  k_conv2p  <<<1024, 192, 0, stream>>>(h1, w2, part);
  k_combine2<<<256, 384, 0, stream>>>(part, g2, b2, h2);
  k_conv3p  <<<6144, 128, 0, stream>>>(h2, w3, part);
  k_combine3<<<384, 384, 0, stream>>>(part, g3, b3, h3);
  k_fcp     <<<384, 256, 0, stream>>>(h3, Wfc, hfcp);
  k_final   <<<1, 128, 0, stream>>>(hfcp, bfc, out);
}